// Round 2
// baseline (1093.526 us; speedup 1.0000x reference)
//
#include <hip/hip_runtime.h>
#include <math.h>

#define BIGI (1 << 30)

// ---- workspace layout (4-byte units) ----
// [0, 16384): k_minmax partials (2048 x int4), dead after k_prep; then h1s
//             (64x256 floats) written by k_lstm<0> (strictly later in stream).
#define PM_OFF   0
#define H1S_OFF  0
#define MM_OFF   16384     // 64 x 4 ints final minmax (persists for heads cumsum)
#define XG_OFF   16640     // 64 x 1024 floats (xg0, then overwritten by xg1)
// total = 82176 * 4 = 328,704 bytes (same footprint as previous round)

// ---- output layout (floats) ----
#define OUT_DELTAS 0       // (4,5,4)
#define OUT_PBB    80      // (4,5,4)
#define OUT_LOC    160     // (4,5,2)
#define OUT_SCL    200     // (4,5,2)
#define OUT_MF     240     // (4,16,256)
#define OUT_CONF   16624   // (4,5)
#define OUT_BBOX   16644   // (4,16,4)

__device__ __forceinline__ float sigmoidf_(float x) { return 1.0f / (1.0f + expf(-x)); }

// ---------------- kernel 1: per-image-chunk mask min/max partials ----------------
// grid = 64 images * 32 chunks, block = 256. Each thread: 32 float4 = 512B.
// No atomics, no init kernel: each block writes its own partial int4.
__global__ __launch_bounds__(256) void k_minmax(const float4* __restrict__ pred,
                                                int* __restrict__ pm) {
    int img = blockIdx.x >> 5;
    int chunk = blockIdx.x & 31;
    int tid = threadIdx.x;
    int base = img * 262144 + chunk * 8192 + tid;
    int xmn = BIGI, xmx = -1, ymn = BIGI, ymx = -1;
#pragma unroll 4
    for (int i = 0; i < 32; ++i) {
        int idx4 = base + i * 256;
        float4 v = pred[idx4];
        int x = (idx4 << 2) & 1023;
        int y = (idx4 >> 8) & 1023;
        bool m0 = v.x > 0.5f, m1 = v.y > 0.5f, m2 = v.z > 0.5f, m3 = v.w > 0.5f;
        int cmn = m0 ? x : (m1 ? x + 1 : (m2 ? x + 2 : (m3 ? x + 3 : BIGI)));
        int cmx = m3 ? x + 3 : (m2 ? x + 2 : (m1 ? x + 1 : (m0 ? x : -1)));
        xmn = min(xmn, cmn);
        xmx = max(xmx, cmx);
        if (m0 | m1 | m2 | m3) { ymn = min(ymn, y); ymx = max(ymx, y); }
    }
    for (int off = 32; off > 0; off >>= 1) {
        xmn = min(xmn, __shfl_down(xmn, off));
        xmx = max(xmx, __shfl_down(xmx, off));
        ymn = min(ymn, __shfl_down(ymn, off));
        ymx = max(ymx, __shfl_down(ymx, off));
    }
    __shared__ int red[4][4];
    int wave = tid >> 6;
    if ((tid & 63) == 0) { red[0][wave] = xmn; red[1][wave] = xmx; red[2][wave] = ymn; red[3][wave] = ymx; }
    __syncthreads();
    if (tid == 0) {
        xmn = min(min(red[0][0], red[0][1]), min(red[0][2], red[0][3]));
        xmx = max(max(red[1][0], red[1][1]), max(red[1][2], red[1][3]));
        ymn = min(min(red[2][0], red[2][1]), min(red[2][2], red[2][3]));
        ymx = max(max(red[3][0], red[3][1]), max(red[3][2], red[3][3]));
        ((int4*)pm)[blockIdx.x] = make_int4(xmn, xmx, ymn, ymx);
    }
}

// ---------------- kernel 2: reduce partials + bbox + pos-MLP + xg0 (+ whh L3 warm) ----
// 64 wgs (one per image), 256 threads.
__global__ __launch_bounds__(256) void k_prep(const int* __restrict__ pm,
    int* __restrict__ mm,
    const float* __restrict__ pe_w1, const float* __restrict__ pe_b1,
    const float* __restrict__ pe_w2, const float* __restrict__ pe_b2,
    const float* __restrict__ wih0, const float* __restrict__ bih0,
    const float* __restrict__ bhh0,
    const float* __restrict__ whh0, const float* __restrict__ whh1,
    float* __restrict__ xg, float* __restrict__ out) {
    __shared__ float bb[4];
    __shared__ __align__(16) float p1[256];
    __shared__ __align__(16) float p2[256];
    int w = blockIdx.x, tid = threadIdx.x;

    // reduce the 32 chunk partials for this image (wave 0 only)
    if (tid < 64) {
        int xmn = BIGI, xmx = -1, ymn = BIGI, ymx = -1;
        if (tid < 32) {
            int4 v = ((const int4*)pm)[w * 32 + tid];
            xmn = v.x; xmx = v.y; ymn = v.z; ymx = v.w;
        }
        for (int off = 32; off > 0; off >>= 1) {
            xmn = min(xmn, __shfl_down(xmn, off));
            xmx = max(xmx, __shfl_down(xmx, off));
            ymn = min(ymn, __shfl_down(ymn, off));
            ymx = max(ymx, __shfl_down(ymx, off));
        }
        if (tid == 0) {
            mm[w * 4 + 0] = xmn; mm[w * 4 + 1] = xmx;
            mm[w * 4 + 2] = ymn; mm[w * 4 + 3] = ymx;
            float cx, cy, bw, bh;
            if (xmx >= 0) {
                cx = (float)(xmn + xmx) * (0.5f / 1024.0f);
                cy = (float)(ymn + ymx) * (0.5f / 1024.0f);
                bw = (float)(xmx - xmn) * (1.0f / 1024.0f);
                bh = (float)(ymx - ymn) * (1.0f / 1024.0f);
            } else { cx = 0.5f; cy = 0.5f; bw = 0.1f; bh = 0.1f; }
            bb[0] = cx; bb[1] = cy; bb[2] = bw; bb[3] = bh;
            out[OUT_BBOX + w * 4 + 0] = cx; out[OUT_BBOX + w * 4 + 1] = cy;
            out[OUT_BBOX + w * 4 + 2] = bw; out[OUT_BBOX + w * 4 + 3] = bh;
        }
    }
    __syncthreads();
    {   // pos1
        float v = bb[0] * pe_w1[tid] + bb[1] * pe_w1[256 + tid] +
                  bb[2] * pe_w1[512 + tid] + bb[3] * pe_w1[768 + tid] + pe_b1[tid];
        p1[tid] = fmaxf(v, 0.0f);
    }
    __syncthreads();
    {   // pos2 (stays in LDS)
        float acc = pe_b2[tid];
#pragma unroll 4
        for (int k = 0; k < 256; ++k) acc += p1[k] * pe_w2[k * 256 + tid];
        p2[tid] = fmaxf(acc, 0.0f);
    }
    // L3-warm whh0/whh1 for the narrow k_lstm readers (2 MB total across 64 wgs)
    float wsum = 0.0f;
    for (int i = tid; i < 4096; i += 256) wsum += whh0[w * 4096 + i] + whh1[w * 4096 + i];
    __syncthreads();
    {   // xg0 row w: thread handles 4 gate cols. biases bih+bhh folded in.
        float4 a = ((const float4*)bih0)[tid];
        float4 a2 = ((const float4*)bhh0)[tid];
        a.x += a2.x; a.y += a2.y; a.z += a2.z; a.w += a2.w;
        const float4* w4 = (const float4*)wih0;   // row stride 256 float4
        const float4* s4 = (const float4*)p2;
#pragma unroll 8
        for (int k4 = 0; k4 < 64; ++k4) {
            float4 hv = s4[k4];
            float4 w0 = w4[(k4 * 4 + 0) * 256 + tid];
            float4 w1 = w4[(k4 * 4 + 1) * 256 + tid];
            float4 w2 = w4[(k4 * 4 + 2) * 256 + tid];
            float4 w3 = w4[(k4 * 4 + 3) * 256 + tid];
            a.x += hv.x * w0.x + hv.y * w1.x + hv.z * w2.x + hv.w * w3.x;
            a.y += hv.x * w0.y + hv.y * w1.y + hv.z * w2.y + hv.w * w3.y;
            a.z += hv.x * w0.z + hv.y * w1.z + hv.z * w2.z + hv.w * w3.z;
            a.w += hv.x * w0.w + hv.y * w1.w + hv.z * w2.w + hv.w * w3.w;
        }
        ((float4*)(xg + w * 1024))[tid] = a;
        if (wsum == 1.2345e30f) xg[w * 1024] = wsum;  // keep warm loads alive (never true)
    }
}

// ---------------- kernel 3: xg1 = h1s @ wih1 + bih1 + bhh1 ----------------
// 64 wgs (one per image-row of h1s), 256 threads, thread -> 4 cols.
__global__ __launch_bounds__(256) void k_xg1(const float* __restrict__ h1s,
    const float* __restrict__ wih1, const float* __restrict__ bih1,
    const float* __restrict__ bhh1, float* __restrict__ xg) {
    __shared__ __align__(16) float4 s4[64];
    int w = blockIdx.x, tid = threadIdx.x;
    if (tid < 64) s4[tid] = ((const float4*)(h1s + w * 256))[tid];
    __syncthreads();
    float4 a = ((const float4*)bih1)[tid];
    float4 a2 = ((const float4*)bhh1)[tid];
    a.x += a2.x; a.y += a2.y; a.z += a2.z; a.w += a2.w;
    const float4* w4 = (const float4*)wih1;
#pragma unroll 8
    for (int k4 = 0; k4 < 64; ++k4) {
        float4 hv = s4[k4];
        float4 w0 = w4[(k4 * 4 + 0) * 256 + tid];
        float4 w1 = w4[(k4 * 4 + 1) * 256 + tid];
        float4 w2 = w4[(k4 * 4 + 2) * 256 + tid];
        float4 w3 = w4[(k4 * 4 + 3) * 256 + tid];
        a.x += hv.x * w0.x + hv.y * w1.x + hv.z * w2.x + hv.w * w3.x;
        a.y += hv.x * w0.y + hv.y * w1.y + hv.z * w2.y + hv.w * w3.y;
        a.z += hv.x * w0.z + hv.y * w1.z + hv.z * w2.z + hv.w * w3.z;
        a.w += hv.x * w0.w + hv.y * w1.w + hv.z * w2.w + hv.w * w3.w;
    }
    ((float4*)(xg + w * 1024))[tid] = a;
}

// ---------------- kernel 4: LSTM recurrence, one wg per batch ----------------
// 4 wgs x 1024 threads (16 waves = 4/SIMD). Thread t owns gate col t:
// whh[:,t] = 64 float4 in VGPRs with FULLY STATIC indices (dynamic t-loop never
// indexes a register array -> no scratch). h broadcast via LDS b128 reads
// (same-address broadcast, conflict-free). xg re-read from L2 each step.
template <int LAYER>
__global__ __launch_bounds__(1024, 4) void k_lstm(
    const float* __restrict__ whh, const float* __restrict__ xg,
    float* __restrict__ h1s, float* __restrict__ out,
    const int* __restrict__ mm,
    const float* __restrict__ mp_w1, const float* __restrict__ mp_b1,
    const float* __restrict__ mp_w2, const float* __restrict__ mp_b2,
    const float* __restrict__ mp_w3, const float* __restrict__ mp_b3,
    const float* __restrict__ cf_w1, const float* __restrict__ cf_b1,
    const float* __restrict__ cf_w2, const float* __restrict__ cf_b2) {
    __shared__ __align__(16) float hsm[256];
    __shared__ float gates[1024];
    const int tid = threadIdx.x;
    const int b = blockIdx.x;

    // resident column of whh: 64 float4 = 256 VGPRs, all indices static
    float4 wv[64];
#pragma unroll 64
    for (int k4 = 0; k4 < 64; ++k4) {
        wv[k4].x = whh[(k4 * 4 + 0) * 1024 + tid];
        wv[k4].y = whh[(k4 * 4 + 1) * 1024 + tid];
        wv[k4].z = whh[(k4 * 4 + 2) * 1024 + tid];
        wv[k4].w = whh[(k4 * 4 + 3) * 1024 + tid];
    }
    float cst = 0.0f;
    const float* xgb = xg + b * 16384 + tid;

    for (int t = 0; t < 16; ++t) {
        float acc = xgb[t * 1024];
        if (t) {
            const float4* h4 = (const float4*)hsm;
#pragma unroll 64
            for (int k4 = 0; k4 < 64; ++k4) {
                float4 h = h4[k4];
                acc += h.x * wv[k4].x + h.y * wv[k4].y + h.z * wv[k4].z + h.w * wv[k4].w;
            }
        }
        gates[tid] = acc;
        __syncthreads();
        if (tid < 256) {
            float gi = gates[tid], gf = gates[256 + tid];
            float gg = gates[512 + tid], go = gates[768 + tid];
            float i_ = sigmoidf_(gi), f_ = sigmoidf_(gf);
            float g_ = tanhf(gg), o_ = sigmoidf_(go);
            cst = f_ * cst + i_ * g_;
            float h = o_ * tanhf(cst);
            hsm[tid] = h;
            if (LAYER == 0) h1s[(b * 16 + t) * 256 + tid] = h;
            else out[OUT_MF + (b * 16 + t) * 256 + tid] = h;
        }
        __syncthreads();
    }

    if (LAYER == 1) {  // heads for this batch; lh = hsm (h at t=15)
        float* x1 = gates;         // 256
        float* c1 = gates + 256;   // 128
        float* x2 = gates + 384;   // 128
        float* dl = gates + 512;   // 20
        const float* lh = hsm;
        if (tid < 256) {
            float a = mp_b1[tid];
#pragma unroll 4
            for (int k = 0; k < 256; ++k) a += lh[k] * mp_w1[k * 256 + tid];
            x1[tid] = fmaxf(a, 0.0f);
        } else if (tid < 384) {
            int j = tid - 256;
            float a = cf_b1[j];
#pragma unroll 4
            for (int k = 0; k < 256; ++k) a += lh[k] * cf_w1[k * 128 + j];
            c1[j] = fmaxf(a, 0.0f);
        }
        __syncthreads();
        if (tid < 128) {
            float a = mp_b2[tid];
#pragma unroll 4
            for (int k = 0; k < 256; ++k) a += x1[k] * mp_w2[k * 128 + tid];
            x2[tid] = fmaxf(a, 0.0f);
        } else if (tid < 133) {
            int j = tid - 128;
            float a = cf_b2[j];
#pragma unroll 4
            for (int k = 0; k < 128; ++k) a += c1[k] * cf_w2[k * 5 + j];
            out[OUT_CONF + b * 5 + j] = sigmoidf_(a);
        }
        __syncthreads();
        if (tid < 20) {
            float a = mp_b3[tid];
#pragma unroll 4
            for (int k = 0; k < 128; ++k) a += x2[k] * mp_w3[k * 20 + tid];
            dl[tid] = a;
            out[OUT_DELTAS + b * 20 + tid] = a;
        }
        __syncthreads();
        if (tid < 4) {  // cumsum of deltas onto last bbox (image b*16+15)
            int img = b * 16 + 15;
            int xmn = mm[img * 4 + 0], xmx = mm[img * 4 + 1];
            int ymn = mm[img * 4 + 2], ymx = mm[img * 4 + 3];
            float v;
            if (xmx >= 0) {
                if (tid == 0)      v = (float)(xmn + xmx) * (0.5f / 1024.0f);
                else if (tid == 1) v = (float)(ymn + ymx) * (0.5f / 1024.0f);
                else if (tid == 2) v = (float)(xmx - xmn) * (1.0f / 1024.0f);
                else               v = (float)(ymx - ymn) * (1.0f / 1024.0f);
            } else v = (tid < 2) ? 0.5f : 0.1f;
            float acc = v;
            for (int hh = 0; hh < 5; ++hh) {
                acc += dl[hh * 4 + tid];
                out[OUT_PBB + b * 20 + hh * 4 + tid] = acc;
                if (tid < 2) out[OUT_LOC + b * 10 + hh * 2 + tid] = acc;
                else out[OUT_SCL + b * 10 + hh * 2 + (tid - 2)] = acc;
            }
        }
    }
}

extern "C" void kernel_launch(void* const* d_in, const int* in_sizes, int n_in,
                              void* d_out, int out_size, void* d_ws, size_t ws_size,
                              hipStream_t stream) {
    (void)in_sizes; (void)n_in; (void)out_size; (void)ws_size;
    const float* pred = (const float*)d_in[1];  // d_in[0] = features (unused by reference)
    const float* pe_w1 = (const float*)d_in[2];
    const float* pe_b1 = (const float*)d_in[3];
    const float* pe_w2 = (const float*)d_in[4];
    const float* pe_b2 = (const float*)d_in[5];
    const float* wih0 = (const float*)d_in[6];
    const float* whh0 = (const float*)d_in[7];
    const float* bih0 = (const float*)d_in[8];
    const float* bhh0 = (const float*)d_in[9];
    const float* wih1 = (const float*)d_in[10];
    const float* whh1 = (const float*)d_in[11];
    const float* bih1 = (const float*)d_in[12];
    const float* bhh1 = (const float*)d_in[13];
    const float* mp_w1 = (const float*)d_in[14];
    const float* mp_b1 = (const float*)d_in[15];
    const float* mp_w2 = (const float*)d_in[16];
    const float* mp_b2 = (const float*)d_in[17];
    const float* mp_w3 = (const float*)d_in[18];
    const float* mp_b3 = (const float*)d_in[19];
    const float* cf_w1 = (const float*)d_in[20];
    const float* cf_b1 = (const float*)d_in[21];
    const float* cf_w2 = (const float*)d_in[22];
    const float* cf_b2 = (const float*)d_in[23];
    float* out = (float*)d_out;
    int* wsi = (int*)d_ws;
    float* wsf = (float*)d_ws;

    hipLaunchKernelGGL(k_minmax, dim3(64 * 32), dim3(256), 0, stream,
                       (const float4*)pred, wsi + PM_OFF);
    hipLaunchKernelGGL(k_prep, dim3(64), dim3(256), 0, stream,
                       wsi + PM_OFF, wsi + MM_OFF,
                       pe_w1, pe_b1, pe_w2, pe_b2,
                       wih0, bih0, bhh0, whh0, whh1,
                       wsf + XG_OFF, out);
    hipLaunchKernelGGL(HIP_KERNEL_NAME(k_lstm<0>), dim3(4), dim3(1024), 0, stream,
                       whh0, wsf + XG_OFF, wsf + H1S_OFF, out, wsi + MM_OFF,
                       mp_w1, mp_b1, mp_w2, mp_b2, mp_w3, mp_b3,
                       cf_w1, cf_b1, cf_w2, cf_b2);
    hipLaunchKernelGGL(k_xg1, dim3(64), dim3(256), 0, stream,
                       wsf + H1S_OFF, wih1, bih1, bhh1, wsf + XG_OFF);
    hipLaunchKernelGGL(HIP_KERNEL_NAME(k_lstm<1>), dim3(4), dim3(1024), 0, stream,
                       whh1, wsf + XG_OFF, wsf + H1S_OFF, out, wsi + MM_OFF,
                       mp_w1, mp_b1, mp_w2, mp_b2, mp_w3, mp_b3,
                       cf_w1, cf_b1, cf_w2, cf_b2);
}

// Round 3
// 681.677 us; speedup vs baseline: 1.6042x; 1.6042x over previous
//
#include <hip/hip_runtime.h>
#include <math.h>

#define BIGI (1 << 30)

// ---- workspace layout (4-byte units), total 43328 words = 173 KB ----
#define PM_OFF    0        // 2048 x int4 minmax partials
#define MM_OFF    8192     // 64 x 4 ints final minmax
#define FLAGS_OFF 8448     // 4 batches x 16-int stride (one 64B line per batch)
#define POS2_OFF  8512     // 64 x 256 floats
#define H1S_OFF   24896    // 4 x 16 x 256 floats (layer-0 h history = layer-1 input)
#define H2_OFF    41280    // 4 x 2 x 256 floats (layer-1 h double buffer)

// ---- output layout (floats) ----
#define OUT_DELTAS 0       // (4,5,4)
#define OUT_PBB    80      // (4,5,4)
#define OUT_LOC    160     // (4,5,2)
#define OUT_SCL    200     // (4,5,2)
#define OUT_MF     240     // (4,16,256)
#define OUT_CONF   16624   // (4,5)
#define OUT_BBOX   16644   // (4,16,4)

__device__ __forceinline__ float sigmoidf_(float x) { return 1.0f / (1.0f + expf(-x)); }

// agent-scope (device-coherent) ops; relaxed ordering. Visibility protocol:
// producers __syncthreads() (drains vmcnt in ALL waves) between data stores and
// the flag store; consumers poll flags then load data -- both at coherence point.
__device__ __forceinline__ void cstoref(float* p, float v) {
    __hip_atomic_store(p, v, __ATOMIC_RELAXED, __HIP_MEMORY_SCOPE_AGENT);
}
__device__ __forceinline__ float cloadf(const float* p) {
    return __hip_atomic_load(p, __ATOMIC_RELAXED, __HIP_MEMORY_SCOPE_AGENT);
}
__device__ __forceinline__ int cloadi(const int* p) {
    return __hip_atomic_load(p, __ATOMIC_RELAXED, __HIP_MEMORY_SCOPE_AGENT);
}

// wait until all 8 WGs of this batch reached monotonic step >= target
__device__ __forceinline__ void pollf(const int* fl, int target) {
    if (threadIdx.x == 0) {
        for (;;) {
            int m = cloadi(fl + 0);
            m = min(m, cloadi(fl + 1)); m = min(m, cloadi(fl + 2));
            m = min(m, cloadi(fl + 3)); m = min(m, cloadi(fl + 4));
            m = min(m, cloadi(fl + 5)); m = min(m, cloadi(fl + 6));
            m = min(m, cloadi(fl + 7));
            if (m >= target) break;
            __builtin_amdgcn_s_sleep(2);
        }
    }
    __syncthreads();
}

// ---------------- kernel 1: per-image-chunk mask min/max partials ----------------
__global__ __launch_bounds__(256) void k_minmax(const float4* __restrict__ pred,
                                                int* __restrict__ pm) {
    int img = blockIdx.x >> 5;
    int chunk = blockIdx.x & 31;
    int tid = threadIdx.x;
    int base = img * 262144 + chunk * 8192 + tid;
    int xmn = BIGI, xmx = -1, ymn = BIGI, ymx = -1;
#pragma unroll 4
    for (int i = 0; i < 32; ++i) {
        int idx4 = base + i * 256;
        float4 v = pred[idx4];
        int x = (idx4 << 2) & 1023;
        int y = (idx4 >> 8) & 1023;
        bool m0 = v.x > 0.5f, m1 = v.y > 0.5f, m2 = v.z > 0.5f, m3 = v.w > 0.5f;
        int cmn = m0 ? x : (m1 ? x + 1 : (m2 ? x + 2 : (m3 ? x + 3 : BIGI)));
        int cmx = m3 ? x + 3 : (m2 ? x + 2 : (m1 ? x + 1 : (m0 ? x : -1)));
        xmn = min(xmn, cmn);
        xmx = max(xmx, cmx);
        if (m0 | m1 | m2 | m3) { ymn = min(ymn, y); ymx = max(ymx, y); }
    }
    for (int off = 32; off > 0; off >>= 1) {
        xmn = min(xmn, __shfl_down(xmn, off));
        xmx = max(xmx, __shfl_down(xmx, off));
        ymn = min(ymn, __shfl_down(ymn, off));
        ymx = max(ymx, __shfl_down(ymx, off));
    }
    __shared__ int red[4][4];
    int wave = tid >> 6;
    if ((tid & 63) == 0) { red[0][wave] = xmn; red[1][wave] = xmx; red[2][wave] = ymn; red[3][wave] = ymx; }
    __syncthreads();
    if (tid == 0) {
        xmn = min(min(red[0][0], red[0][1]), min(red[0][2], red[0][3]));
        xmx = max(max(red[1][0], red[1][1]), max(red[1][2], red[1][3]));
        ymn = min(min(red[2][0], red[2][1]), min(red[2][2], red[2][3]));
        ymx = max(max(red[3][0], red[3][1]), max(red[3][2], red[3][3]));
        ((int4*)pm)[blockIdx.x] = make_int4(xmn, xmx, ymn, ymx);
    }
}

// ---------------- kernel 2: reduce partials + bbox + pos-MLP; zero flags ----------
__global__ __launch_bounds__(256) void k_prep(const int* __restrict__ pm,
    int* __restrict__ mm, int* __restrict__ flags,
    const float* __restrict__ pe_w1, const float* __restrict__ pe_b1,
    const float* __restrict__ pe_w2, const float* __restrict__ pe_b2,
    float* __restrict__ pos2, float* __restrict__ out) {
    __shared__ float bb[4];
    __shared__ float p1[256];
    int w = blockIdx.x, tid = threadIdx.x;
    if (w == 0 && tid < 64) flags[tid] = 0;
    if (tid < 64) {
        int xmn = BIGI, xmx = -1, ymn = BIGI, ymx = -1;
        if (tid < 32) {
            int4 v = ((const int4*)pm)[w * 32 + tid];
            xmn = v.x; xmx = v.y; ymn = v.z; ymx = v.w;
        }
        for (int off = 32; off > 0; off >>= 1) {
            xmn = min(xmn, __shfl_down(xmn, off));
            xmx = max(xmx, __shfl_down(xmx, off));
            ymn = min(ymn, __shfl_down(ymn, off));
            ymx = max(ymx, __shfl_down(ymx, off));
        }
        if (tid == 0) {
            mm[w * 4 + 0] = xmn; mm[w * 4 + 1] = xmx;
            mm[w * 4 + 2] = ymn; mm[w * 4 + 3] = ymx;
            float cx, cy, bw, bh;
            if (xmx >= 0) {
                cx = (float)(xmn + xmx) * (0.5f / 1024.0f);
                cy = (float)(ymn + ymx) * (0.5f / 1024.0f);
                bw = (float)(xmx - xmn) * (1.0f / 1024.0f);
                bh = (float)(ymx - ymn) * (1.0f / 1024.0f);
            } else { cx = 0.5f; cy = 0.5f; bw = 0.1f; bh = 0.1f; }
            bb[0] = cx; bb[1] = cy; bb[2] = bw; bb[3] = bh;
            out[OUT_BBOX + w * 4 + 0] = cx; out[OUT_BBOX + w * 4 + 1] = cy;
            out[OUT_BBOX + w * 4 + 2] = bw; out[OUT_BBOX + w * 4 + 3] = bh;
        }
    }
    __syncthreads();
    {
        float v = bb[0] * pe_w1[tid] + bb[1] * pe_w1[256 + tid] +
                  bb[2] * pe_w1[512 + tid] + bb[3] * pe_w1[768 + tid] + pe_b1[tid];
        p1[tid] = fmaxf(v, 0.0f);
    }
    __syncthreads();
    float acc = pe_b2[tid];
#pragma unroll 4
    for (int k = 0; k < 256; ++k) acc += p1[k] * pe_w2[k * 256 + tid];
    pos2[w * 256 + tid] = fmaxf(acc, 0.0f);
}

// ---------------- kernel 3: fused 2-layer LSTM + heads ----------------
// 32 WGs x 256 threads: (b = blk>>3, g = blk&7). WG owns 128 gate cols:
// col(j) = (j>>5)*256 + g*32 + (j&31), j = tid&127; kh = tid>>7 splits k.
// Weight slice (128 floats/thread) lives in VGPRs with STATIC indices only.
// Per-step sync: per-WG monotonic flag (agent store) + 8-flag poll. No RMW.
__global__ __launch_bounds__(256, 1) void k_lstm(
    const float* __restrict__ wih0, const float* __restrict__ whh0,
    const float* __restrict__ bih0, const float* __restrict__ bhh0,
    const float* __restrict__ wih1, const float* __restrict__ whh1,
    const float* __restrict__ bih1, const float* __restrict__ bhh1,
    const float* __restrict__ mp_w1, const float* __restrict__ mp_b1,
    const float* __restrict__ mp_w2, const float* __restrict__ mp_b2,
    const float* __restrict__ mp_w3, const float* __restrict__ mp_b3,
    const float* __restrict__ cf_w1, const float* __restrict__ cf_b1,
    const float* __restrict__ cf_w2, const float* __restrict__ cf_b2,
    const float* __restrict__ pos2, float* __restrict__ h1s,
    float* __restrict__ h2, int* __restrict__ flags,
    const int* __restrict__ mm, float* __restrict__ out) {
    __shared__ float px[4096];     // 16 rows x 256 (X-phase input; heads scratch)
    __shared__ float partX[4096];  // k-half partials for X phase
    __shared__ float xgl[2048];    // xg[t][j] for this WG's 128 cols
    __shared__ float hsm[256];     // broadcast h
    __shared__ float part[256];    // k-half partials for recurrence
    __shared__ float gatesL[128];
    const int tid = threadIdx.x;
    const int b = blockIdx.x >> 3, g = blockIdx.x & 7;
    const int j = tid & 127, kh = tid >> 7;
    const int col = ((j >> 5) << 8) + g * 32 + (j & 31);
    int* flb = flags + b * 16;
    float4 wreg[32];

    for (int layer = 0; layer < 2; ++layer) {
        const float* wih = layer ? wih1 : wih0;
        const float* whh = layer ? whh1 : whh0;
        const float* bih = layer ? bih1 : bih0;
        const float* bhh = layer ? bhh1 : bhh0;

        // ---- X phase: load input rows, compute xg[t][j] for our cols ----
        if (layer == 0) {
            for (int i = tid; i < 4096; i += 256) px[i] = pos2[b * 4096 + i];
        } else {
            pollf(flb, 16);  // all of this batch's h1 outputs stored
            for (int i = tid; i < 4096; i += 256) px[i] = cloadf(&h1s[b * 4096 + i]);
        }
#pragma unroll
        for (int k4 = 0; k4 < 32; ++k4) {  // wih column slice -> VGPRs
            int r = kh * 128 + k4 * 4;
            wreg[k4].x = wih[(r + 0) * 1024 + col];
            wreg[k4].y = wih[(r + 1) * 1024 + col];
            wreg[k4].z = wih[(r + 2) * 1024 + col];
            wreg[k4].w = wih[(r + 3) * 1024 + col];
        }
        __syncthreads();
        for (int t = 0; t < 16; ++t) {
            float a = 0.0f;
            const float4* p4 = (const float4*)&px[t * 256 + kh * 128];
#pragma unroll
            for (int k4 = 0; k4 < 32; ++k4) {
                float4 h4 = p4[k4];
                a += h4.x * wreg[k4].x + h4.y * wreg[k4].y + h4.z * wreg[k4].z + h4.w * wreg[k4].w;
            }
            partX[kh * 2048 + t * 128 + j] = a;
        }
        __syncthreads();
        {   // combine k-halves + fold both biases; thread keeps one col across 8 t's
            float bsum = bih[col] + bhh[col];
            int t0 = tid >> 7;
            for (int i = 0; i < 8; ++i) {
                int t = t0 + 2 * i;
                xgl[t * 128 + j] = partX[t * 128 + j] + partX[2048 + t * 128 + j] + bsum;
            }
        }
#pragma unroll
        for (int k4 = 0; k4 < 32; ++k4) {  // whh column slice -> VGPRs
            int r = kh * 128 + k4 * 4;
            wreg[k4].x = whh[(r + 0) * 1024 + col];
            wreg[k4].y = whh[(r + 1) * 1024 + col];
            wreg[k4].z = whh[(r + 2) * 1024 + col];
            wreg[k4].w = whh[(r + 3) * 1024 + col];
        }
        __syncthreads();

        // ---- 16 recurrent steps ----
        float cst = 0.0f;
        for (int t = 0; t < 16; ++t) {
            if (t) {
                pollf(flb, layer * 16 + t);  // all h[t-1] stores visible
                hsm[tid] = (layer == 0)
                    ? cloadf(&h1s[(b * 16 + t - 1) * 256 + tid])
                    : cloadf(&h2[b * 512 + ((t - 1) & 1) * 256 + tid]);
            }
            __syncthreads();
            float a = 0.0f;
            if (t) {
                const float4* h4p = (const float4*)&hsm[kh * 128];
#pragma unroll
                for (int k4 = 0; k4 < 32; ++k4) {
                    float4 h4 = h4p[k4];
                    a += h4.x * wreg[k4].x + h4.y * wreg[k4].y + h4.z * wreg[k4].z + h4.w * wreg[k4].w;
                }
            }
            part[tid] = a;
            __syncthreads();
            if (tid < 128) gatesL[tid] = part[tid] + part[128 + tid] + xgl[t * 128 + tid];
            __syncthreads();
            if (tid < 32) {
                float gi = gatesL[tid], gf = gatesL[32 + tid];
                float gg = gatesL[64 + tid], go = gatesL[96 + tid];
                float i_ = sigmoidf_(gi), f_ = sigmoidf_(gf);
                float g_ = tanhf(gg), o_ = sigmoidf_(go);
                cst = f_ * cst + i_ * g_;
                float h = o_ * tanhf(cst);
                int unit = g * 32 + tid;
                if (layer == 0) {
                    cstoref(&h1s[(b * 16 + t) * 256 + unit], h);
                } else {
                    cstoref(&h2[b * 512 + (t & 1) * 256 + unit], h);
                    out[OUT_MF + (b * 16 + t) * 256 + unit] = h;
                }
            }
            __syncthreads();  // drains vmcnt in all waves -> h stores visible
            if (tid == 0)
                __hip_atomic_store(&flb[g], layer * 16 + t + 1,
                                   __ATOMIC_RELAXED, __HIP_MEMORY_SCOPE_AGENT);
        }
    }

    // ---- heads: one WG per batch (g==0) ----
    if (g != 0) return;
    pollf(flb, 32);
    float* lh = px;          // 256
    float* x1 = px + 256;    // 256
    float* c1 = px + 512;    // 128
    float* x2 = px + 768;    // 128
    float* dl = px + 896;    // 20
    lh[tid] = cloadf(&h2[b * 512 + 256 + tid]);  // h output t=15 -> slot (15&1)=1
    __syncthreads();
    {
        float a = mp_b1[tid];
#pragma unroll 4
        for (int k = 0; k < 256; ++k) a += lh[k] * mp_w1[k * 256 + tid];
        x1[tid] = fmaxf(a, 0.0f);
    }
    if (tid < 128) {
        float a = cf_b1[tid];
#pragma unroll 4
        for (int k = 0; k < 256; ++k) a += lh[k] * cf_w1[k * 128 + tid];
        c1[tid] = fmaxf(a, 0.0f);
    }
    __syncthreads();
    if (tid < 128) {
        float a = mp_b2[tid];
#pragma unroll 4
        for (int k = 0; k < 256; ++k) a += x1[k] * mp_w2[k * 128 + tid];
        x2[tid] = fmaxf(a, 0.0f);
    } else if (tid < 133) {
        int jj = tid - 128;
        float a = cf_b2[jj];
#pragma unroll 4
        for (int k = 0; k < 128; ++k) a += c1[k] * cf_w2[k * 5 + jj];
        out[OUT_CONF + b * 5 + jj] = sigmoidf_(a);
    }
    __syncthreads();
    if (tid < 20) {
        float a = mp_b3[tid];
#pragma unroll 4
        for (int k = 0; k < 128; ++k) a += x2[k] * mp_w3[k * 20 + tid];
        dl[tid] = a;
        out[OUT_DELTAS + b * 20 + tid] = a;
    }
    __syncthreads();
    if (tid < 4) {  // cumsum of deltas onto last bbox (image b*16+15)
        int img = b * 16 + 15;
        int xmn = mm[img * 4 + 0], xmx = mm[img * 4 + 1];
        int ymn = mm[img * 4 + 2], ymx = mm[img * 4 + 3];
        float v;
        if (xmx >= 0) {
            if (tid == 0)      v = (float)(xmn + xmx) * (0.5f / 1024.0f);
            else if (tid == 1) v = (float)(ymn + ymx) * (0.5f / 1024.0f);
            else if (tid == 2) v = (float)(xmx - xmn) * (1.0f / 1024.0f);
            else               v = (float)(ymx - ymn) * (1.0f / 1024.0f);
        } else v = (tid < 2) ? 0.5f : 0.1f;
        float acc = v;
        for (int hh = 0; hh < 5; ++hh) {
            acc += dl[hh * 4 + tid];
            out[OUT_PBB + b * 20 + hh * 4 + tid] = acc;
            if (tid < 2) out[OUT_LOC + b * 10 + hh * 2 + tid] = acc;
            else out[OUT_SCL + b * 10 + hh * 2 + (tid - 2)] = acc;
        }
    }
}

extern "C" void kernel_launch(void* const* d_in, const int* in_sizes, int n_in,
                              void* d_out, int out_size, void* d_ws, size_t ws_size,
                              hipStream_t stream) {
    (void)in_sizes; (void)n_in; (void)out_size; (void)ws_size;
    const float* pred = (const float*)d_in[1];  // d_in[0] = features (unused)
    const float* pe_w1 = (const float*)d_in[2];
    const float* pe_b1 = (const float*)d_in[3];
    const float* pe_w2 = (const float*)d_in[4];
    const float* pe_b2 = (const float*)d_in[5];
    const float* wih0 = (const float*)d_in[6];
    const float* whh0 = (const float*)d_in[7];
    const float* bih0 = (const float*)d_in[8];
    const float* bhh0 = (const float*)d_in[9];
    const float* wih1 = (const float*)d_in[10];
    const float* whh1 = (const float*)d_in[11];
    const float* bih1 = (const float*)d_in[12];
    const float* bhh1 = (const float*)d_in[13];
    const float* mp_w1 = (const float*)d_in[14];
    const float* mp_b1 = (const float*)d_in[15];
    const float* mp_w2 = (const float*)d_in[16];
    const float* mp_b2 = (const float*)d_in[17];
    const float* mp_w3 = (const float*)d_in[18];
    const float* mp_b3 = (const float*)d_in[19];
    const float* cf_w1 = (const float*)d_in[20];
    const float* cf_b1 = (const float*)d_in[21];
    const float* cf_w2 = (const float*)d_in[22];
    const float* cf_b2 = (const float*)d_in[23];
    float* out = (float*)d_out;
    int* wsi = (int*)d_ws;
    float* wsf = (float*)d_ws;

    hipLaunchKernelGGL(k_minmax, dim3(64 * 32), dim3(256), 0, stream,
                       (const float4*)pred, wsi + PM_OFF);
    hipLaunchKernelGGL(k_prep, dim3(64), dim3(256), 0, stream,
                       wsi + PM_OFF, wsi + MM_OFF, wsi + FLAGS_OFF,
                       pe_w1, pe_b1, pe_w2, pe_b2,
                       wsf + POS2_OFF, out);
    hipLaunchKernelGGL(k_lstm, dim3(32), dim3(256), 0, stream,
                       wih0, whh0, bih0, bhh0,
                       wih1, whh1, bih1, bhh1,
                       mp_w1, mp_b1, mp_w2, mp_b2, mp_w3, mp_b3,
                       cf_w1, cf_b1, cf_w2, cf_b2,
                       wsf + POS2_OFF, wsf + H1S_OFF, wsf + H2_OFF,
                       wsi + FLAGS_OFF, wsi + MM_OFF, out);
}

// Round 4
// 658.155 us; speedup vs baseline: 1.6615x; 1.0357x over previous
//
#include <hip/hip_runtime.h>
#include <math.h>

#define BIGI (1 << 30)

// ---- workspace layout (4-byte units), total 61696 words = 247 KB ----
#define PM_OFF    0        // 2048 x int4 minmax partials
#define MM_OFF    8192     // 64 x 4 ints final minmax
#define POS2_OFF  8448     // 64 x 256 floats
#define HT0_OFF   24832    // 4 x 16 x 256 tagged uint64 (layer-0 h history), 8B aligned
#define HT2_OFF   57600    // 4 x 2 x 256 tagged uint64 (layer-1 h double buffer)
#define HT_WORDS  36864    // words to zero each launch (tags must reset)

// ---- output layout (floats) ----
#define OUT_DELTAS 0       // (4,5,4)
#define OUT_PBB    80      // (4,5,4)
#define OUT_LOC    160     // (4,5,2)
#define OUT_SCL    200     // (4,5,2)
#define OUT_MF     240     // (4,16,256)
#define OUT_CONF   16624   // (4,5)
#define OUT_BBOX   16644   // (4,16,4)

__device__ __forceinline__ float sigmoidf_(float x) { return 1.0f / (1.0f + expf(-x)); }

// ---- self-signaling h exchange: one 8-byte atomic payload = (tag<<32)|h ----
// Producer's single agent-scope store IS the signal (no flags, no fences).
// Each slot is written exactly once per launch with a unique tag (no ABA);
// k_prep zeroes all tags each launch (graph-replay safe).
__device__ __forceinline__ void storeh(unsigned long long* p, float h, int tag) {
    unsigned long long v =
        ((unsigned long long)(unsigned)tag << 32) | (unsigned long long)__float_as_uint(h);
    __hip_atomic_store(p, v, __ATOMIC_RELAXED, __HIP_MEMORY_SCOPE_AGENT);
}
__device__ __forceinline__ float pollh(const unsigned long long* p, int tag) {
    unsigned long long v = __hip_atomic_load(p, __ATOMIC_RELAXED, __HIP_MEMORY_SCOPE_AGENT);
    while ((int)(v >> 32) != tag) {
        __builtin_amdgcn_s_sleep(1);
        v = __hip_atomic_load(p, __ATOMIC_RELAXED, __HIP_MEMORY_SCOPE_AGENT);
    }
    return __uint_as_float((unsigned)v);
}

// ---------------- kernel 1: per-image-chunk mask min/max partials ----------------
__global__ __launch_bounds__(256) void k_minmax(const float4* __restrict__ pred,
                                                int* __restrict__ pm) {
    int img = blockIdx.x >> 5;
    int chunk = blockIdx.x & 31;
    int tid = threadIdx.x;
    int base = img * 262144 + chunk * 8192 + tid;
    int xmn = BIGI, xmx = -1, ymn = BIGI, ymx = -1;
#pragma unroll 4
    for (int i = 0; i < 32; ++i) {
        int idx4 = base + i * 256;
        float4 v = pred[idx4];
        int x = (idx4 << 2) & 1023;
        int y = (idx4 >> 8) & 1023;
        bool m0 = v.x > 0.5f, m1 = v.y > 0.5f, m2 = v.z > 0.5f, m3 = v.w > 0.5f;
        int cmn = m0 ? x : (m1 ? x + 1 : (m2 ? x + 2 : (m3 ? x + 3 : BIGI)));
        int cmx = m3 ? x + 3 : (m2 ? x + 2 : (m1 ? x + 1 : (m0 ? x : -1)));
        xmn = min(xmn, cmn);
        xmx = max(xmx, cmx);
        if (m0 | m1 | m2 | m3) { ymn = min(ymn, y); ymx = max(ymx, y); }
    }
    for (int off = 32; off > 0; off >>= 1) {
        xmn = min(xmn, __shfl_down(xmn, off));
        xmx = max(xmx, __shfl_down(xmx, off));
        ymn = min(ymn, __shfl_down(ymn, off));
        ymx = max(ymx, __shfl_down(ymx, off));
    }
    __shared__ int red[4][4];
    int wave = tid >> 6;
    if ((tid & 63) == 0) { red[0][wave] = xmn; red[1][wave] = xmx; red[2][wave] = ymn; red[3][wave] = ymx; }
    __syncthreads();
    if (tid == 0) {
        xmn = min(min(red[0][0], red[0][1]), min(red[0][2], red[0][3]));
        xmx = max(max(red[1][0], red[1][1]), max(red[1][2], red[1][3]));
        ymn = min(min(red[2][0], red[2][1]), min(red[2][2], red[2][3]));
        ymx = max(max(red[3][0], red[3][1]), max(red[3][2], red[3][3]));
        ((int4*)pm)[blockIdx.x] = make_int4(xmn, xmx, ymn, ymx);
    }
}

// ------- kernel 2: reduce partials + bbox + pos-MLP; zero tagged-h region -------
__global__ __launch_bounds__(256) void k_prep(const int* __restrict__ pm,
    int* __restrict__ mm, int* __restrict__ ht,
    const float* __restrict__ pe_w1, const float* __restrict__ pe_b1,
    const float* __restrict__ pe_w2, const float* __restrict__ pe_b2,
    float* __restrict__ pos2, float* __restrict__ out) {
    __shared__ float bb[4];
    __shared__ float p1[256];
    int w = blockIdx.x, tid = threadIdx.x;
    // zero all tag payloads (re-poison for next launch / graph replay)
    for (int i = w * 256 + tid; i < HT_WORDS; i += 64 * 256) ht[i] = 0;
    if (tid < 64) {
        int xmn = BIGI, xmx = -1, ymn = BIGI, ymx = -1;
        if (tid < 32) {
            int4 v = ((const int4*)pm)[w * 32 + tid];
            xmn = v.x; xmx = v.y; ymn = v.z; ymx = v.w;
        }
        for (int off = 32; off > 0; off >>= 1) {
            xmn = min(xmn, __shfl_down(xmn, off));
            xmx = max(xmx, __shfl_down(xmx, off));
            ymn = min(ymn, __shfl_down(ymn, off));
            ymx = max(ymx, __shfl_down(ymx, off));
        }
        if (tid == 0) {
            mm[w * 4 + 0] = xmn; mm[w * 4 + 1] = xmx;
            mm[w * 4 + 2] = ymn; mm[w * 4 + 3] = ymx;
            float cx, cy, bw, bh;
            if (xmx >= 0) {
                cx = (float)(xmn + xmx) * (0.5f / 1024.0f);
                cy = (float)(ymn + ymx) * (0.5f / 1024.0f);
                bw = (float)(xmx - xmn) * (1.0f / 1024.0f);
                bh = (float)(ymx - ymn) * (1.0f / 1024.0f);
            } else { cx = 0.5f; cy = 0.5f; bw = 0.1f; bh = 0.1f; }
            bb[0] = cx; bb[1] = cy; bb[2] = bw; bb[3] = bh;
            out[OUT_BBOX + w * 4 + 0] = cx; out[OUT_BBOX + w * 4 + 1] = cy;
            out[OUT_BBOX + w * 4 + 2] = bw; out[OUT_BBOX + w * 4 + 3] = bh;
        }
    }
    __syncthreads();
    {
        float v = bb[0] * pe_w1[tid] + bb[1] * pe_w1[256 + tid] +
                  bb[2] * pe_w1[512 + tid] + bb[3] * pe_w1[768 + tid] + pe_b1[tid];
        p1[tid] = fmaxf(v, 0.0f);
    }
    __syncthreads();
    float acc = pe_b2[tid];
#pragma unroll 4
    for (int k = 0; k < 256; ++k) acc += p1[k] * pe_w2[k * 256 + tid];
    pos2[w * 256 + tid] = fmaxf(acc, 0.0f);
}

// ---------------- kernel 3: fused 2-layer LSTM + heads ----------------
// 32 WGs x 256 threads: (b = blk>>3, g = blk&7). WG owns 128 gate cols:
// col(j) = (j>>5)*256 + g*32 + (j&31), j = tid&127; kh = tid>>7 splits k.
// Weight slice (128 floats/thread) in VGPRs, static indices only (VGPR~236).
// Cross-WG h exchange: self-signaling tagged 8B payloads, ONE round trip/step.
__global__ __launch_bounds__(256, 1) void k_lstm(
    const float* __restrict__ wih0, const float* __restrict__ whh0,
    const float* __restrict__ bih0, const float* __restrict__ bhh0,
    const float* __restrict__ wih1, const float* __restrict__ whh1,
    const float* __restrict__ bih1, const float* __restrict__ bhh1,
    const float* __restrict__ mp_w1, const float* __restrict__ mp_b1,
    const float* __restrict__ mp_w2, const float* __restrict__ mp_b2,
    const float* __restrict__ mp_w3, const float* __restrict__ mp_b3,
    const float* __restrict__ cf_w1, const float* __restrict__ cf_b1,
    const float* __restrict__ cf_w2, const float* __restrict__ cf_b2,
    const float* __restrict__ pos2, unsigned long long* __restrict__ hT0,
    unsigned long long* __restrict__ hT2,
    const int* __restrict__ mm, float* __restrict__ out) {
    __shared__ float px[4096];     // 16 rows x 256 (X-phase input; heads scratch)
    __shared__ float partX[4096];  // k-half partials for X phase
    __shared__ float xgl[2048];    // xg[t][j] for this WG's 128 cols
    __shared__ float hsm[256];     // broadcast h
    __shared__ float part[256];    // k-half partials for recurrence
    __shared__ float gatesL[128];
    const int tid = threadIdx.x;
    const int b = blockIdx.x >> 3, g = blockIdx.x & 7;
    const int j = tid & 127, kh = tid >> 7;
    const int col = ((j >> 5) << 8) + g * 32 + (j & 31);
    float4 wreg[32];

    for (int layer = 0; layer < 2; ++layer) {
        const float* wih = layer ? wih1 : wih0;
        const float* whh = layer ? whh1 : whh0;
        const float* bih = layer ? bih1 : bih0;
        const float* bhh = layer ? bhh1 : bhh0;

        // ---- X phase: load input rows, compute xg[t][j] for our cols ----
        if (layer == 0) {
            for (int i = tid; i < 4096; i += 256) px[i] = pos2[b * 4096 + i];
        } else {
            for (int i = tid; i < 4096; i += 256) {
                int t = i >> 8, unit = i & 255;
                px[i] = pollh(&hT0[((b * 16 + t) << 8) + unit], t + 1);
            }
        }
#pragma unroll
        for (int k4 = 0; k4 < 32; ++k4) {  // wih column slice -> VGPRs
            int r = kh * 128 + k4 * 4;
            wreg[k4].x = wih[(r + 0) * 1024 + col];
            wreg[k4].y = wih[(r + 1) * 1024 + col];
            wreg[k4].z = wih[(r + 2) * 1024 + col];
            wreg[k4].w = wih[(r + 3) * 1024 + col];
        }
        __syncthreads();
        for (int t = 0; t < 16; ++t) {
            float a = 0.0f;
            const float4* p4 = (const float4*)&px[t * 256 + kh * 128];
#pragma unroll
            for (int k4 = 0; k4 < 32; ++k4) {
                float4 h4 = p4[k4];
                a += h4.x * wreg[k4].x + h4.y * wreg[k4].y + h4.z * wreg[k4].z + h4.w * wreg[k4].w;
            }
            partX[kh * 2048 + t * 128 + j] = a;
        }
        __syncthreads();
        {   // combine k-halves + fold both biases
            float bsum = bih[col] + bhh[col];
            int t0 = tid >> 7;
            for (int i = 0; i < 8; ++i) {
                int t = t0 + 2 * i;
                xgl[t * 128 + j] = partX[t * 128 + j] + partX[2048 + t * 128 + j] + bsum;
            }
        }
#pragma unroll
        for (int k4 = 0; k4 < 32; ++k4) {  // whh column slice -> VGPRs
            int r = kh * 128 + k4 * 4;
            wreg[k4].x = whh[(r + 0) * 1024 + col];
            wreg[k4].y = whh[(r + 1) * 1024 + col];
            wreg[k4].z = whh[(r + 2) * 1024 + col];
            wreg[k4].w = whh[(r + 3) * 1024 + col];
        }
        __syncthreads();

        // ---- 16 recurrent steps ----
        float cst = 0.0f;
        for (int t = 0; t < 16; ++t) {
            if (t) {  // fetch h[t-1]: each thread polls its unit's tagged payload
                const unsigned long long* src = (layer == 0)
                    ? &hT0[((b * 16 + (t - 1)) << 8) + tid]
                    : &hT2[(((b << 1) | ((t - 1) & 1)) << 8) + tid];
                hsm[tid] = pollh(src, layer * 16 + t);
            }
            __syncthreads();
            float a = 0.0f;
            if (t) {
                const float4* h4p = (const float4*)&hsm[kh * 128];
#pragma unroll
                for (int k4 = 0; k4 < 32; ++k4) {
                    float4 h4 = h4p[k4];
                    a += h4.x * wreg[k4].x + h4.y * wreg[k4].y + h4.z * wreg[k4].z + h4.w * wreg[k4].w;
                }
            }
            part[tid] = a;
            __syncthreads();
            if (tid < 128) gatesL[tid] = part[tid] + part[128 + tid] + xgl[t * 128 + tid];
            __syncthreads();
            if (tid < 32) {
                float gi = gatesL[tid], gf = gatesL[32 + tid];
                float gg = gatesL[64 + tid], go = gatesL[96 + tid];
                float i_ = sigmoidf_(gi), f_ = sigmoidf_(gf);
                float g_ = tanhf(gg), o_ = sigmoidf_(go);
                cst = f_ * cst + i_ * g_;
                float h = o_ * tanhf(cst);
                int unit = g * 32 + tid;
                int tag = layer * 16 + t + 1;
                if (layer == 0) {
                    storeh(&hT0[((b * 16 + t) << 8) + unit], h, tag);
                } else {
                    storeh(&hT2[(((b << 1) | (t & 1)) << 8) + unit], h, tag);
                    out[OUT_MF + (b * 16 + t) * 256 + unit] = h;
                }
            }
            // no trailing barrier needed: hsm/part/gatesL rewrites are fenced by
            // the next iteration's barriers; the tagged store is the only signal.
        }
    }

    // ---- heads: one WG per batch (g==0) ----
    if (g != 0) return;
    __syncthreads();
    float* lh = px;          // 256
    float* x1 = px + 256;    // 256
    float* c1 = px + 512;    // 128
    float* x2 = px + 768;    // 128
    float* dl = px + 896;    // 20
    lh[tid] = pollh(&hT2[((b << 1) | 1) << 8 | tid], 32);  // h at t=15 (slot 1)
    __syncthreads();
    {
        float a = mp_b1[tid];
#pragma unroll 4
        for (int k = 0; k < 256; ++k) a += lh[k] * mp_w1[k * 256 + tid];
        x1[tid] = fmaxf(a, 0.0f);
    }
    if (tid < 128) {
        float a = cf_b1[tid];
#pragma unroll 4
        for (int k = 0; k < 256; ++k) a += lh[k] * cf_w1[k * 128 + tid];
        c1[tid] = fmaxf(a, 0.0f);
    }
    __syncthreads();
    if (tid < 128) {
        float a = mp_b2[tid];
#pragma unroll 4
        for (int k = 0; k < 256; ++k) a += x1[k] * mp_w2[k * 128 + tid];
        x2[tid] = fmaxf(a, 0.0f);
    } else if (tid < 133) {
        int jj = tid - 128;
        float a = cf_b2[jj];
#pragma unroll 4
        for (int k = 0; k < 128; ++k) a += c1[k] * cf_w2[k * 5 + jj];
        out[OUT_CONF + b * 5 + jj] = sigmoidf_(a);
    }
    __syncthreads();
    if (tid < 20) {
        float a = mp_b3[tid];
#pragma unroll 4
        for (int k = 0; k < 128; ++k) a += x2[k] * mp_w3[k * 20 + tid];
        dl[tid] = a;
        out[OUT_DELTAS + b * 20 + tid] = a;
    }
    __syncthreads();
    if (tid < 4) {  // cumsum of deltas onto last bbox (image b*16+15)
        int img = b * 16 + 15;
        int xmn = mm[img * 4 + 0], xmx = mm[img * 4 + 1];
        int ymn = mm[img * 4 + 2], ymx = mm[img * 4 + 3];
        float v;
        if (xmx >= 0) {
            if (tid == 0)      v = (float)(xmn + xmx) * (0.5f / 1024.0f);
            else if (tid == 1) v = (float)(ymn + ymx) * (0.5f / 1024.0f);
            else if (tid == 2) v = (float)(xmx - xmn) * (1.0f / 1024.0f);
            else               v = (float)(ymx - ymn) * (1.0f / 1024.0f);
        } else v = (tid < 2) ? 0.5f : 0.1f;
        float acc = v;
        for (int hh = 0; hh < 5; ++hh) {
            acc += dl[hh * 4 + tid];
            out[OUT_PBB + b * 20 + hh * 4 + tid] = acc;
            if (tid < 2) out[OUT_LOC + b * 10 + hh * 2 + tid] = acc;
            else out[OUT_SCL + b * 10 + hh * 2 + (tid - 2)] = acc;
        }
    }
}

extern "C" void kernel_launch(void* const* d_in, const int* in_sizes, int n_in,
                              void* d_out, int out_size, void* d_ws, size_t ws_size,
                              hipStream_t stream) {
    (void)in_sizes; (void)n_in; (void)out_size; (void)ws_size;
    const float* pred = (const float*)d_in[1];  // d_in[0] = features (unused)
    const float* pe_w1 = (const float*)d_in[2];
    const float* pe_b1 = (const float*)d_in[3];
    const float* pe_w2 = (const float*)d_in[4];
    const float* pe_b2 = (const float*)d_in[5];
    const float* wih0 = (const float*)d_in[6];
    const float* whh0 = (const float*)d_in[7];
    const float* bih0 = (const float*)d_in[8];
    const float* bhh0 = (const float*)d_in[9];
    const float* wih1 = (const float*)d_in[10];
    const float* whh1 = (const float*)d_in[11];
    const float* bih1 = (const float*)d_in[12];
    const float* bhh1 = (const float*)d_in[13];
    const float* mp_w1 = (const float*)d_in[14];
    const float* mp_b1 = (const float*)d_in[15];
    const float* mp_w2 = (const float*)d_in[16];
    const float* mp_b2 = (const float*)d_in[17];
    const float* mp_w3 = (const float*)d_in[18];
    const float* mp_b3 = (const float*)d_in[19];
    const float* cf_w1 = (const float*)d_in[20];
    const float* cf_b1 = (const float*)d_in[21];
    const float* cf_w2 = (const float*)d_in[22];
    const float* cf_b2 = (const float*)d_in[23];
    float* out = (float*)d_out;
    int* wsi = (int*)d_ws;
    float* wsf = (float*)d_ws;

    hipLaunchKernelGGL(k_minmax, dim3(64 * 32), dim3(256), 0, stream,
                       (const float4*)pred, wsi + PM_OFF);
    hipLaunchKernelGGL(k_prep, dim3(64), dim3(256), 0, stream,
                       wsi + PM_OFF, wsi + MM_OFF, wsi + HT0_OFF,
                       pe_w1, pe_b1, pe_w2, pe_b2,
                       wsf + POS2_OFF, out);
    hipLaunchKernelGGL(k_lstm, dim3(32), dim3(256), 0, stream,
                       wih0, whh0, bih0, bhh0,
                       wih1, whh1, bih1, bhh1,
                       mp_w1, mp_b1, mp_w2, mp_b2, mp_w3, mp_b3,
                       cf_w1, cf_b1, cf_w2, cf_b2,
                       wsf + POS2_OFF,
                       (unsigned long long*)(wsi + HT0_OFF),
                       (unsigned long long*)(wsi + HT2_OFF),
                       wsi + MM_OFF, out);
}

// Round 5
// 603.632 us; speedup vs baseline: 1.8116x; 1.0903x over previous
//
#include <hip/hip_runtime.h>
#include <math.h>

#define BIGI (1 << 30)

// ---- workspace layout (4-byte units), total 45057 words ≈ 180 KB ----
#define PM_OFF    0        // 2048 x int4 minmax partials
#define HT0_OFF   8192     // 4 x 16 x 256 tagged u64 (h1 history), 8B aligned
#define HT2_OFF   40960    // 4 x 2 x 256 tagged u64 (h2 double buffer)
#define DONE_OFF  45056    // filler-exit counter
#define ZERO_BEG  8192     // zero [ZERO_BEG, ZERO_END) each launch (tags + done)
#define ZERO_END  45057

// ---- output layout (floats) ----
#define OUT_DELTAS 0       // (4,5,4)
#define OUT_PBB    80      // (4,5,4)
#define OUT_LOC    160     // (4,5,2)
#define OUT_SCL    200     // (4,5,2)
#define OUT_MF     240     // (4,16,256)
#define OUT_CONF   16624   // (4,5)
#define OUT_BBOX   16644   // (4,16,4)

__device__ __forceinline__ float sigmoidf_(float x) { return 1.0f / (1.0f + expf(-x)); }

// ---- self-signaling h exchange: one 8-byte atomic payload = (tag<<32)|h ----
__device__ __forceinline__ void storeh(unsigned long long* p, float h, int tag) {
    unsigned long long v =
        ((unsigned long long)(unsigned)tag << 32) | (unsigned long long)__float_as_uint(h);
    __hip_atomic_store(p, v, __ATOMIC_RELAXED, __HIP_MEMORY_SCOPE_AGENT);
}
__device__ __forceinline__ float pollh(const unsigned long long* p, int tag) {
    unsigned long long v = __hip_atomic_load(p, __ATOMIC_RELAXED, __HIP_MEMORY_SCOPE_AGENT);
    while ((int)(v >> 32) != tag) {
        __builtin_amdgcn_s_sleep(1);
        v = __hip_atomic_load(p, __ATOMIC_RELAXED, __HIP_MEMORY_SCOPE_AGENT);
    }
    return __uint_as_float((unsigned)v);
}

// ---------------- kernel 1: minmax partials + zero tag region ----------------
__global__ __launch_bounds__(256) void k_minmax(const float4* __restrict__ pred,
                                                int* __restrict__ ws) {
    int tid = threadIdx.x;
    // zero tags + done counter (re-poison for graph replay); covered by blocks 0..144
    for (int i = ZERO_BEG + blockIdx.x * 256 + tid; i < ZERO_END; i += 2048 * 256)
        ws[i] = 0;
    int img = blockIdx.x >> 5;
    int chunk = blockIdx.x & 31;
    int base = img * 262144 + chunk * 8192 + tid;
    int xmn = BIGI, xmx = -1, ymn = BIGI, ymx = -1;
#pragma unroll 4
    for (int i = 0; i < 32; ++i) {
        int idx4 = base + i * 256;
        float4 v = pred[idx4];
        int x = (idx4 << 2) & 1023;
        int y = (idx4 >> 8) & 1023;
        bool m0 = v.x > 0.5f, m1 = v.y > 0.5f, m2 = v.z > 0.5f, m3 = v.w > 0.5f;
        int cmn = m0 ? x : (m1 ? x + 1 : (m2 ? x + 2 : (m3 ? x + 3 : BIGI)));
        int cmx = m3 ? x + 3 : (m2 ? x + 2 : (m1 ? x + 1 : (m0 ? x : -1)));
        xmn = min(xmn, cmn);
        xmx = max(xmx, cmx);
        if (m0 | m1 | m2 | m3) { ymn = min(ymn, y); ymx = max(ymx, y); }
    }
    for (int off = 32; off > 0; off >>= 1) {
        xmn = min(xmn, __shfl_down(xmn, off));
        xmx = max(xmx, __shfl_down(xmx, off));
        ymn = min(ymn, __shfl_down(ymn, off));
        ymx = max(ymx, __shfl_down(ymx, off));
    }
    __shared__ int red[4][4];
    int wave = tid >> 6;
    if ((tid & 63) == 0) { red[0][wave] = xmn; red[1][wave] = xmx; red[2][wave] = ymn; red[3][wave] = ymx; }
    __syncthreads();
    if (tid == 0) {
        xmn = min(min(red[0][0], red[0][1]), min(red[0][2], red[0][3]));
        xmx = max(max(red[1][0], red[1][1]), max(red[1][2], red[1][3]));
        ymn = min(min(red[2][0], red[2][1]), min(red[2][2], red[2][3]));
        ymx = max(max(red[3][0], red[3][1]), max(red[3][2], red[3][3]));
        ((int4*)(ws + PM_OFF))[blockIdx.x] = make_int4(xmn, xmx, ymn, ymx);
    }
}

__device__ __forceinline__ void mk_bbox(int xmn, int xmx, int ymn, int ymx,
                                        float* o) {
    if (xmx >= 0) {
        o[0] = (float)(xmn + xmx) * (0.5f / 1024.0f);
        o[1] = (float)(ymn + ymx) * (0.5f / 1024.0f);
        o[2] = (float)(xmx - xmn) * (1.0f / 1024.0f);
        o[3] = (float)(ymx - ymn) * (1.0f / 1024.0f);
    } else { o[0] = 0.5f; o[1] = 0.5f; o[2] = 0.1f; o[3] = 0.1f; }
}

// ---------------- kernel 2: fused pos-MLP + pipelined 2-layer LSTM + heads -------
// blocks 0..31: layer 0 (b=blk>>3, g=blk&7); 32..63: layer 1; 64..191: clock filler.
// Each WG owns 128 gate cols: col(j)=(j>>5)*256+g*32+(j&31), j=tid&127, kh=tid>>7.
// wih AND whh slices register-resident (64 float4 ~ 256 VGPR, static indices).
// Layers pipelined: L1 step t polls h1[t] (lag 1 behind L0) -> ~17 sequential rounds.
__global__ __launch_bounds__(256, 1) void k_fused(
    const float* __restrict__ pe_w1, const float* __restrict__ pe_b1,
    const float* __restrict__ pe_w2, const float* __restrict__ pe_b2,
    const float* __restrict__ wih0, const float* __restrict__ whh0,
    const float* __restrict__ bih0, const float* __restrict__ bhh0,
    const float* __restrict__ wih1, const float* __restrict__ whh1,
    const float* __restrict__ bih1, const float* __restrict__ bhh1,
    const float* __restrict__ mp_w1, const float* __restrict__ mp_b1,
    const float* __restrict__ mp_w2, const float* __restrict__ mp_b2,
    const float* __restrict__ mp_w3, const float* __restrict__ mp_b3,
    const float* __restrict__ cf_w1, const float* __restrict__ cf_b1,
    const float* __restrict__ cf_w2, const float* __restrict__ cf_b2,
    const int4* __restrict__ pm4, unsigned long long* __restrict__ hT0,
    unsigned long long* __restrict__ hT2, int* __restrict__ done,
    float* __restrict__ out) {
    __shared__ float sPX[4096];   // L0: pos2 rows; L1 g==0: heads scratch
    __shared__ float sP1[4096];   // L0: pos-MLP hidden
    __shared__ float sBB[64];     // L0: 16 bboxes; L1 heads: bbox15
    __shared__ float hsm[256];
    __shared__ float h2sm[256];
    __shared__ float part[256];
    const int tid = threadIdx.x, blk = blockIdx.x;

    if (blk >= 64) {  // ---- clock-keeper filler: spin FMA until all heads done ----
        float a0 = 0.f, a1 = 1.f, a2 = 2.f, a3 = 3.f, a4 = 4.f, a5 = 5.f, a6 = 6.f, a7 = 7.f;
        const float m = 1.0000001f, c = 0.9999999f;
        for (;;) {
#pragma unroll
            for (int i = 0; i < 128; ++i) {
                a0 = fmaf(a0, m, c); a1 = fmaf(a1, m, c); a2 = fmaf(a2, m, c); a3 = fmaf(a3, m, c);
                a4 = fmaf(a4, m, c); a5 = fmaf(a5, m, c); a6 = fmaf(a6, m, c); a7 = fmaf(a7, m, c);
            }
            if (__hip_atomic_load(done, __ATOMIC_RELAXED, __HIP_MEMORY_SCOPE_AGENT) >= 4) break;
        }
        asm volatile("" :: "v"(a0), "v"(a1), "v"(a2), "v"(a3), "v"(a4), "v"(a5), "v"(a6), "v"(a7));
        return;
    }

    const int layer = blk >> 5;
    const int b = (blk >> 3) & 3, g = blk & 7;
    const int j = tid & 127, kh = tid >> 7;
    const int col = ((j >> 5) << 8) + g * 32 + (j & 31);

    // ---- L0 prologue: bbox for 16 images + pos-MLP (pos2 -> sPX) ----
    if (layer == 0) {
        {
            int il = tid >> 4, c2 = (tid & 15) * 2;
            int4 A = pm4[(b * 16 + il) * 32 + c2];
            int4 B = pm4[(b * 16 + il) * 32 + c2 + 1];
            int xmn = min(A.x, B.x), xmx = max(A.y, B.y);
            int ymn = min(A.z, B.z), ymx = max(A.w, B.w);
            for (int off = 8; off > 0; off >>= 1) {
                xmn = min(xmn, __shfl_down(xmn, off, 16));
                xmx = max(xmx, __shfl_down(xmx, off, 16));
                ymn = min(ymn, __shfl_down(ymn, off, 16));
                ymx = max(ymx, __shfl_down(ymx, off, 16));
            }
            if ((tid & 15) == 0) {
                float bb[4];
                mk_bbox(xmn, xmx, ymn, ymx, bb);
                sBB[il * 4 + 0] = bb[0]; sBB[il * 4 + 1] = bb[1];
                sBB[il * 4 + 2] = bb[2]; sBB[il * 4 + 3] = bb[3];
                if (g == 0) {
                    out[OUT_BBOX + (b * 16 + il) * 4 + 0] = bb[0];
                    out[OUT_BBOX + (b * 16 + il) * 4 + 1] = bb[1];
                    out[OUT_BBOX + (b * 16 + il) * 4 + 2] = bb[2];
                    out[OUT_BBOX + (b * 16 + il) * 4 + 3] = bb[3];
                }
            }
        }
        __syncthreads();
        {   // p1[i][tid]
            float w0 = pe_w1[tid], w1 = pe_w1[256 + tid];
            float w2 = pe_w1[512 + tid], w3 = pe_w1[768 + tid], b1v = pe_b1[tid];
#pragma unroll
            for (int i = 0; i < 16; ++i) {
                float v = sBB[i * 4] * w0 + sBB[i * 4 + 1] * w1 +
                          sBB[i * 4 + 2] * w2 + sBB[i * 4 + 3] * w3 + b1v;
                sP1[i * 256 + tid] = fmaxf(v, 0.0f);
            }
        }
        __syncthreads();
        {   // pos2[i][tid] for all 16 rows
            float acc[16];
            float b2v = pe_b2[tid];
#pragma unroll
            for (int i = 0; i < 16; ++i) acc[i] = b2v;
            for (int k = 0; k < 256; ++k) {
                float wv = pe_w2[k * 256 + tid];
#pragma unroll
                for (int i = 0; i < 16; ++i) acc[i] += sP1[i * 256 + k] * wv;
            }
#pragma unroll
            for (int i = 0; i < 16; ++i) sPX[i * 256 + tid] = fmaxf(acc[i], 0.0f);
        }
        __syncthreads();
    }

    // ---- load weight slices into VGPRs (static indices only) ----
    const float* wih = layer ? wih1 : wih0;
    const float* whh = layer ? whh1 : whh0;
    const float* bih = layer ? bih1 : bih0;
    const float* bhh = layer ? bhh1 : bhh0;
    float4 wi[32], wh[32];
#pragma unroll
    for (int k4 = 0; k4 < 32; ++k4) {
        int r = kh * 128 + k4 * 4;
        wi[k4].x = wih[(r + 0) * 1024 + col];
        wi[k4].y = wih[(r + 1) * 1024 + col];
        wi[k4].z = wih[(r + 2) * 1024 + col];
        wi[k4].w = wih[(r + 3) * 1024 + col];
        wh[k4].x = whh[(r + 0) * 1024 + col];
        wh[k4].y = whh[(r + 1) * 1024 + col];
        wh[k4].z = whh[(r + 2) * 1024 + col];
        wh[k4].w = whh[(r + 3) * 1024 + col];
    }
    float bs0 = 0.f, bs1 = 0.f, bs2 = 0.f, bs3 = 0.f;
    if (tid < 32) {
        int u = g * 32 + tid;
        bs0 = bih[u] + bhh[u];
        bs1 = bih[256 + u] + bhh[256 + u];
        bs2 = bih[512 + u] + bhh[512 + u];
        bs3 = bih[768 + u] + bhh[768 + u];
    }

    // ---- recurrence: 2 syncs/step; cross-WG via tagged payloads ----
    float cst = 0.0f;
    for (int t = 0; t < 16; ++t) {
        if (layer == 0) {
            if (t) hsm[tid] = pollh(&hT0[((b * 16 + t - 1) << 8) + tid], t);
        } else {
            hsm[tid] = pollh(&hT0[((b * 16 + t) << 8) + tid], t + 1);
            if (t) h2sm[tid] = pollh(&hT2[(((b << 1) | ((t - 1) & 1)) << 8) + tid], t);
        }
        __syncthreads();
        float a = 0.0f;
        if (layer == 0) {
            const float4* xr = (const float4*)&sPX[t * 256 + kh * 128];
#pragma unroll
            for (int k = 0; k < 32; ++k) {
                float4 x = xr[k];
                a += x.x * wi[k].x + x.y * wi[k].y + x.z * wi[k].z + x.w * wi[k].w;
            }
            if (t) {
                const float4* hr = (const float4*)&hsm[kh * 128];
#pragma unroll
                for (int k = 0; k < 32; ++k) {
                    float4 h = hr[k];
                    a += h.x * wh[k].x + h.y * wh[k].y + h.z * wh[k].z + h.w * wh[k].w;
                }
            }
        } else {
            const float4* xr = (const float4*)&hsm[kh * 128];
#pragma unroll
            for (int k = 0; k < 32; ++k) {
                float4 x = xr[k];
                a += x.x * wi[k].x + x.y * wi[k].y + x.z * wi[k].z + x.w * wi[k].w;
            }
            if (t) {
                const float4* hr = (const float4*)&h2sm[kh * 128];
#pragma unroll
                for (int k = 0; k < 32; ++k) {
                    float4 h = hr[k];
                    a += h.x * wh[k].x + h.y * wh[k].y + h.z * wh[k].z + h.w * wh[k].w;
                }
            }
        }
        part[tid] = a;
        __syncthreads();
        if (tid < 32) {
            float gi = part[tid] + part[128 + tid] + bs0;
            float gf = part[32 + tid] + part[160 + tid] + bs1;
            float gg = part[64 + tid] + part[192 + tid] + bs2;
            float go = part[96 + tid] + part[224 + tid] + bs3;
            float i_ = sigmoidf_(gi), f_ = sigmoidf_(gf);
            float g_ = tanhf(gg), o_ = sigmoidf_(go);
            cst = f_ * cst + i_ * g_;
            float h = o_ * tanhf(cst);
            int unit = g * 32 + tid;
            if (layer == 0) {
                storeh(&hT0[((b * 16 + t) << 8) + unit], h, t + 1);
            } else {
                storeh(&hT2[(((b << 1) | (t & 1)) << 8) + unit], h, t + 1);
                out[OUT_MF + (b * 16 + t) * 256 + unit] = h;
            }
        }
        // no trailing sync: hsm/part rewrites are fenced by next iteration's syncs
    }
    if (layer == 0 || g != 0) return;

    // ---- heads (L1 g==0, one WG per batch) ----
    float* lh = sPX;          // 256
    float* x1 = sPX + 256;    // 256
    float* c1 = sPX + 512;    // 128
    float* x2 = sPX + 640;    // 128
    float* dl = sPX + 768;    // 20
    lh[tid] = pollh(&hT2[(((b << 1) | 1) << 8) + tid], 16);
    if (tid < 32) {  // bbox of image b*16+15 for cumsum base
        int4 v = pm4[(b * 16 + 15) * 32 + tid];
        int xmn = v.x, xmx = v.y, ymn = v.z, ymx = v.w;
        for (int off = 16; off > 0; off >>= 1) {
            xmn = min(xmn, __shfl_down(xmn, off, 32));
            xmx = max(xmx, __shfl_down(xmx, off, 32));
            ymn = min(ymn, __shfl_down(ymn, off, 32));
            ymx = max(ymx, __shfl_down(ymx, off, 32));
        }
        if (tid == 0) mk_bbox(xmn, xmx, ymn, ymx, sBB);
    }
    __syncthreads();
    {
        float a = mp_b1[tid];
#pragma unroll 4
        for (int k = 0; k < 256; ++k) a += lh[k] * mp_w1[k * 256 + tid];
        x1[tid] = fmaxf(a, 0.0f);
    }
    if (tid < 128) {
        float a = cf_b1[tid];
#pragma unroll 4
        for (int k = 0; k < 256; ++k) a += lh[k] * cf_w1[k * 128 + tid];
        c1[tid] = fmaxf(a, 0.0f);
    }
    __syncthreads();
    if (tid < 128) {
        float a = mp_b2[tid];
#pragma unroll 4
        for (int k = 0; k < 256; ++k) a += x1[k] * mp_w2[k * 128 + tid];
        x2[tid] = fmaxf(a, 0.0f);
    } else if (tid < 133) {
        int jj = tid - 128;
        float a = cf_b2[jj];
#pragma unroll 4
        for (int k = 0; k < 128; ++k) a += c1[k] * cf_w2[k * 5 + jj];
        out[OUT_CONF + b * 5 + jj] = sigmoidf_(a);
    }
    __syncthreads();
    if (tid < 20) {
        float a = mp_b3[tid];
#pragma unroll 4
        for (int k = 0; k < 128; ++k) a += x2[k] * mp_w3[k * 20 + tid];
        dl[tid] = a;
        out[OUT_DELTAS + b * 20 + tid] = a;
    }
    __syncthreads();
    if (tid < 4) {
        float acc = sBB[tid];
        for (int hh = 0; hh < 5; ++hh) {
            acc += dl[hh * 4 + tid];
            out[OUT_PBB + b * 20 + hh * 4 + tid] = acc;
            if (tid < 2) out[OUT_LOC + b * 10 + hh * 2 + tid] = acc;
            else out[OUT_SCL + b * 10 + hh * 2 + (tid - 2)] = acc;
        }
    }
    __syncthreads();
    if (tid == 0) atomicAdd(done, 1);  // release clock-keeper fillers
}

extern "C" void kernel_launch(void* const* d_in, const int* in_sizes, int n_in,
                              void* d_out, int out_size, void* d_ws, size_t ws_size,
                              hipStream_t stream) {
    (void)in_sizes; (void)n_in; (void)out_size; (void)ws_size;
    const float* pred = (const float*)d_in[1];  // d_in[0] = features (unused)
    const float* pe_w1 = (const float*)d_in[2];
    const float* pe_b1 = (const float*)d_in[3];
    const float* pe_w2 = (const float*)d_in[4];
    const float* pe_b2 = (const float*)d_in[5];
    const float* wih0 = (const float*)d_in[6];
    const float* whh0 = (const float*)d_in[7];
    const float* bih0 = (const float*)d_in[8];
    const float* bhh0 = (const float*)d_in[9];
    const float* wih1 = (const float*)d_in[10];
    const float* whh1 = (const float*)d_in[11];
    const float* bih1 = (const float*)d_in[12];
    const float* bhh1 = (const float*)d_in[13];
    const float* mp_w1 = (const float*)d_in[14];
    const float* mp_b1 = (const float*)d_in[15];
    const float* mp_w2 = (const float*)d_in[16];
    const float* mp_b2 = (const float*)d_in[17];
    const float* mp_w3 = (const float*)d_in[18];
    const float* mp_b3 = (const float*)d_in[19];
    const float* cf_w1 = (const float*)d_in[20];
    const float* cf_b1 = (const float*)d_in[21];
    const float* cf_w2 = (const float*)d_in[22];
    const float* cf_b2 = (const float*)d_in[23];
    float* out = (float*)d_out;
    int* wsi = (int*)d_ws;

    hipLaunchKernelGGL(k_minmax, dim3(64 * 32), dim3(256), 0, stream,
                       (const float4*)pred, wsi);
    hipLaunchKernelGGL(k_fused, dim3(192), dim3(256), 0, stream,
                       pe_w1, pe_b1, pe_w2, pe_b2,
                       wih0, whh0, bih0, bhh0,
                       wih1, whh1, bih1, bhh1,
                       mp_w1, mp_b1, mp_w2, mp_b2, mp_w3, mp_b3,
                       cf_w1, cf_b1, cf_w2, cf_b2,
                       (const int4*)(wsi + PM_OFF),
                       (unsigned long long*)(wsi + HT0_OFF),
                       (unsigned long long*)(wsi + HT2_OFF),
                       wsi + DONE_OFF, out);
}

// Round 6
// 594.386 us; speedup vs baseline: 1.8398x; 1.0156x over previous
//
#include <hip/hip_runtime.h>
#include <math.h>

#define BIGI (1 << 30)

// ---- workspace layout (4-byte units), total 45057 words ~ 180 KB ----
#define PM_OFF    0        // 2048 x int4 minmax partials
#define HT0_OFF   8192     // 4 x 16 x 256 tagged u64 (h1 history), 8B aligned
#define HT2_OFF   40960    // 4 x 2 x 256 tagged u64 (h2 double buffer)
#define DONE_OFF  45056    // filler-exit counter
#define ZERO_BEG  8192     // zero [ZERO_BEG, ZERO_END) each launch (tags + done)
#define ZERO_END  45057

// ---- output layout (floats) ----
#define OUT_DELTAS 0       // (4,5,4)
#define OUT_PBB    80      // (4,5,4)
#define OUT_LOC    160     // (4,5,2)
#define OUT_SCL    200     // (4,5,2)
#define OUT_MF     240     // (4,16,256)
#define OUT_CONF   16624   // (4,5)
#define OUT_BBOX   16644   // (4,16,4)

__device__ __forceinline__ float sigmoidf_(float x) { return 1.0f / (1.0f + expf(-x)); }

// ---- self-signaling h exchange: one 8-byte atomic payload = (tag<<32)|h ----
__device__ __forceinline__ void storeh(unsigned long long* p, float h, int tag) {
    unsigned long long v =
        ((unsigned long long)(unsigned)tag << 32) | (unsigned long long)__float_as_uint(h);
    __hip_atomic_store(p, v, __ATOMIC_RELAXED, __HIP_MEMORY_SCOPE_AGENT);
}
__device__ __forceinline__ float pollh(const unsigned long long* p, int tag) {
    unsigned long long v = __hip_atomic_load(p, __ATOMIC_RELAXED, __HIP_MEMORY_SCOPE_AGENT);
    while ((int)(v >> 32) != tag) {
        __builtin_amdgcn_s_sleep(1);
        v = __hip_atomic_load(p, __ATOMIC_RELAXED, __HIP_MEMORY_SCOPE_AGENT);
    }
    return __uint_as_float((unsigned)v);
}
// dual poll: issue both loads before spinning on either (one serial detect latency)
__device__ __forceinline__ float2 pollh2(const unsigned long long* p1, int tag1,
                                         const unsigned long long* p2, int tag2) {
    unsigned long long v1 = __hip_atomic_load(p1, __ATOMIC_RELAXED, __HIP_MEMORY_SCOPE_AGENT);
    unsigned long long v2 = __hip_atomic_load(p2, __ATOMIC_RELAXED, __HIP_MEMORY_SCOPE_AGENT);
    while ((int)(v1 >> 32) != tag1) {
        __builtin_amdgcn_s_sleep(1);
        v1 = __hip_atomic_load(p1, __ATOMIC_RELAXED, __HIP_MEMORY_SCOPE_AGENT);
    }
    while ((int)(v2 >> 32) != tag2) {
        __builtin_amdgcn_s_sleep(1);
        v2 = __hip_atomic_load(p2, __ATOMIC_RELAXED, __HIP_MEMORY_SCOPE_AGENT);
    }
    return make_float2(__uint_as_float((unsigned)v1), __uint_as_float((unsigned)v2));
}

// ---------------- kernel 1: minmax partials + zero tag region ----------------
__global__ __launch_bounds__(256) void k_minmax(const float4* __restrict__ pred,
                                                int* __restrict__ ws) {
    int tid = threadIdx.x;
    for (int i = ZERO_BEG + blockIdx.x * 256 + tid; i < ZERO_END; i += 2048 * 256)
        ws[i] = 0;
    int img = blockIdx.x >> 5;
    int chunk = blockIdx.x & 31;
    int base = img * 262144 + chunk * 8192 + tid;
    int xmn = BIGI, xmx = -1, ymn = BIGI, ymx = -1;
#pragma unroll 4
    for (int i = 0; i < 32; ++i) {
        int idx4 = base + i * 256;
        float4 v = pred[idx4];
        int x = (idx4 << 2) & 1023;
        int y = (idx4 >> 8) & 1023;
        bool m0 = v.x > 0.5f, m1 = v.y > 0.5f, m2 = v.z > 0.5f, m3 = v.w > 0.5f;
        int cmn = m0 ? x : (m1 ? x + 1 : (m2 ? x + 2 : (m3 ? x + 3 : BIGI)));
        int cmx = m3 ? x + 3 : (m2 ? x + 2 : (m1 ? x + 1 : (m0 ? x : -1)));
        xmn = min(xmn, cmn);
        xmx = max(xmx, cmx);
        if (m0 | m1 | m2 | m3) { ymn = min(ymn, y); ymx = max(ymx, y); }
    }
    for (int off = 32; off > 0; off >>= 1) {
        xmn = min(xmn, __shfl_down(xmn, off));
        xmx = max(xmx, __shfl_down(xmx, off));
        ymn = min(ymn, __shfl_down(ymn, off));
        ymx = max(ymx, __shfl_down(ymx, off));
    }
    __shared__ int red[4][4];
    int wave = tid >> 6;
    if ((tid & 63) == 0) { red[0][wave] = xmn; red[1][wave] = xmx; red[2][wave] = ymn; red[3][wave] = ymx; }
    __syncthreads();
    if (tid == 0) {
        xmn = min(min(red[0][0], red[0][1]), min(red[0][2], red[0][3]));
        xmx = max(max(red[1][0], red[1][1]), max(red[1][2], red[1][3]));
        ymn = min(min(red[2][0], red[2][1]), min(red[2][2], red[2][3]));
        ymx = max(max(red[3][0], red[3][1]), max(red[3][2], red[3][3]));
        ((int4*)(ws + PM_OFF))[blockIdx.x] = make_int4(xmn, xmx, ymn, ymx);
    }
}

__device__ __forceinline__ void mk_bbox(int xmn, int xmx, int ymn, int ymx, float* o) {
    if (xmx >= 0) {
        o[0] = (float)(xmn + xmx) * (0.5f / 1024.0f);
        o[1] = (float)(ymn + ymx) * (0.5f / 1024.0f);
        o[2] = (float)(xmx - xmn) * (1.0f / 1024.0f);
        o[3] = (float)(ymx - ymn) * (1.0f / 1024.0f);
    } else { o[0] = 0.5f; o[1] = 0.5f; o[2] = 0.1f; o[3] = 0.1f; }
}

// ---------------- kernel 2: fused pos-MLP + pipelined 2-layer LSTM + heads -------
// blocks 0..63: layer 0; 64..127: layer 1; 128..255: clock fillers.
// Decomposition: 16 WGs per (layer,batch): b=(blk>>4)&3, g=blk&15. WG owns 64
// gate-cols: col = gate*256 + g*16 + u (gate=cidx>>4, u=cidx&15, cidx=tid&63);
// kq=tid>>6 splits k into 4 quarters of 64 rows. Weight slice per thread =
// wi[16]+wh[16] float4 = 128 VGPRs -- the allocator-proven resident regime (R3).
// Cross-WG h via self-signaling tagged payloads; L1 lags L0 by 1 (17 rounds).
__global__ __launch_bounds__(256, 1) void k_fused(
    const float* __restrict__ pe_w1, const float* __restrict__ pe_b1,
    const float* __restrict__ pe_w2, const float* __restrict__ pe_b2,
    const float* __restrict__ wih0, const float* __restrict__ whh0,
    const float* __restrict__ bih0, const float* __restrict__ bhh0,
    const float* __restrict__ wih1, const float* __restrict__ whh1,
    const float* __restrict__ bih1, const float* __restrict__ bhh1,
    const float* __restrict__ mp_w1, const float* __restrict__ mp_b1,
    const float* __restrict__ mp_w2, const float* __restrict__ mp_b2,
    const float* __restrict__ mp_w3, const float* __restrict__ mp_b3,
    const float* __restrict__ cf_w1, const float* __restrict__ cf_b1,
    const float* __restrict__ cf_w2, const float* __restrict__ cf_b2,
    const int4* __restrict__ pm4, unsigned long long* __restrict__ hT0,
    unsigned long long* __restrict__ hT2, int* __restrict__ done,
    float* __restrict__ out) {
    __shared__ __align__(16) float sPX[4096];  // L0: pos2 rows; L1 g==0: heads scratch
    __shared__ __align__(16) float sP1[4096];  // L0: pos-MLP hidden
    __shared__ float xgl[1024];                // L0: xg[t][cidx] (bias folded)
    __shared__ __align__(16) float hsm[256];
    __shared__ __align__(16) float h2sm[256];
    __shared__ float partA[256];
    __shared__ float sBB[64];
    const int tid = threadIdx.x, blk = blockIdx.x;

    if (blk >= 128) {  // ---- clock-keeper filler: dense FMA, rare done-checks ----
        float a0 = 0.f, a1 = 1.f, a2 = 2.f, a3 = 3.f, a4 = 4.f, a5 = 5.f, a6 = 6.f, a7 = 7.f;
        const float m = 1.0000001f, c = 0.9999999f;
        for (;;) {
#pragma unroll 8
            for (int i = 0; i < 512; ++i) {
                a0 = fmaf(a0, m, c); a1 = fmaf(a1, m, c); a2 = fmaf(a2, m, c); a3 = fmaf(a3, m, c);
                a4 = fmaf(a4, m, c); a5 = fmaf(a5, m, c); a6 = fmaf(a6, m, c); a7 = fmaf(a7, m, c);
            }
            if (__hip_atomic_load(done, __ATOMIC_RELAXED, __HIP_MEMORY_SCOPE_AGENT) >= 4) break;
        }
        asm volatile("" :: "v"(a0), "v"(a1), "v"(a2), "v"(a3), "v"(a4), "v"(a5), "v"(a6), "v"(a7));
        return;
    }

    const int layer = blk >> 6;
    const int b = (blk >> 4) & 3, g = blk & 15;
    const int cidx = tid & 63, kq = tid >> 6;
    const int gate = cidx >> 4, u = cidx & 15;
    const int col = gate * 256 + g * 16 + u;
    const int krow0 = kq * 64;

    const float* wih = layer ? wih1 : wih0;
    const float* whh = layer ? whh1 : whh0;
    const float* bih = layer ? bih1 : bih0;
    const float* bhh = layer ? bhh1 : bhh0;

    float4 wvi[16];
#pragma unroll
    for (int k4 = 0; k4 < 16; ++k4) {  // wih column slice -> VGPRs (64 regs)
        int r = krow0 + k4 * 4;
        wvi[k4].x = wih[(r + 0) * 1024 + col];
        wvi[k4].y = wih[(r + 1) * 1024 + col];
        wvi[k4].z = wih[(r + 2) * 1024 + col];
        wvi[k4].w = wih[(r + 3) * 1024 + col];
    }

    // ---- L0 prologue: bbox + pos-MLP + xg precompute into LDS ----
    if (layer == 0) {
        {
            int il = tid >> 4, c2 = (tid & 15) * 2;
            int4 A = pm4[(b * 16 + il) * 32 + c2];
            int4 B = pm4[(b * 16 + il) * 32 + c2 + 1];
            int xmn = min(A.x, B.x), xmx = max(A.y, B.y);
            int ymn = min(A.z, B.z), ymx = max(A.w, B.w);
            for (int off = 8; off > 0; off >>= 1) {
                xmn = min(xmn, __shfl_down(xmn, off, 16));
                xmx = max(xmx, __shfl_down(xmx, off, 16));
                ymn = min(ymn, __shfl_down(ymn, off, 16));
                ymx = max(ymx, __shfl_down(ymx, off, 16));
            }
            if ((tid & 15) == 0) {
                float bb[4];
                mk_bbox(xmn, xmx, ymn, ymx, bb);
                sBB[il * 4 + 0] = bb[0]; sBB[il * 4 + 1] = bb[1];
                sBB[il * 4 + 2] = bb[2]; sBB[il * 4 + 3] = bb[3];
                if (g == 0) {
                    out[OUT_BBOX + (b * 16 + il) * 4 + 0] = bb[0];
                    out[OUT_BBOX + (b * 16 + il) * 4 + 1] = bb[1];
                    out[OUT_BBOX + (b * 16 + il) * 4 + 2] = bb[2];
                    out[OUT_BBOX + (b * 16 + il) * 4 + 3] = bb[3];
                }
            }
        }
        __syncthreads();
        {   // p1[i][tid]
            float w0 = pe_w1[tid], w1 = pe_w1[256 + tid];
            float w2 = pe_w1[512 + tid], w3 = pe_w1[768 + tid], b1v = pe_b1[tid];
#pragma unroll
            for (int i = 0; i < 16; ++i) {
                float v = sBB[i * 4] * w0 + sBB[i * 4 + 1] * w1 +
                          sBB[i * 4 + 2] * w2 + sBB[i * 4 + 3] * w3 + b1v;
                sP1[i * 256 + tid] = fmaxf(v, 0.0f);
            }
        }
        __syncthreads();
        {   // pos2[i][tid]
            float acc[16];
            float b2v = pe_b2[tid];
#pragma unroll
            for (int i = 0; i < 16; ++i) acc[i] = b2v;
            for (int k = 0; k < 256; ++k) {
                float wv = pe_w2[k * 256 + tid];
#pragma unroll
                for (int i = 0; i < 16; ++i) acc[i] += sP1[i * 256 + k] * wv;
            }
#pragma unroll
            for (int i = 0; i < 16; ++i) sPX[i * 256 + tid] = fmaxf(acc[i], 0.0f);
        }
        __syncthreads();
        // xg[t][cidx] = pos2[t] . wih[:,col] + bih[col] + bhh[col]
        float bsum = 0.0f;
        if (tid < 64) {
            int cc = (tid >> 4) * 256 + g * 16 + (tid & 15);
            bsum = bih[cc] + bhh[cc];
        }
        for (int t = 0; t < 16; ++t) {
            const float4* xr = (const float4*)&sPX[t * 256 + krow0];
            float a = 0.0f;
#pragma unroll
            for (int k = 0; k < 16; ++k) {
                float4 x = xr[k];
                a += x.x * wvi[k].x + x.y * wvi[k].y + x.z * wvi[k].z + x.w * wvi[k].w;
            }
            partA[tid] = a;
            __syncthreads();
            if (tid < 64)
                xgl[t * 64 + tid] = partA[tid] + partA[64 + tid] +
                                    partA[128 + tid] + partA[192 + tid] + bsum;
            __syncthreads();
        }
    }

    float4 wvh[16];
#pragma unroll
    for (int k4 = 0; k4 < 16; ++k4) {  // whh column slice -> VGPRs (64 regs)
        int r = krow0 + k4 * 4;
        wvh[k4].x = whh[(r + 0) * 1024 + col];
        wvh[k4].y = whh[(r + 1) * 1024 + col];
        wvh[k4].z = whh[(r + 2) * 1024 + col];
        wvh[k4].w = whh[(r + 3) * 1024 + col];
    }
    float bs0 = 0.f, bs1 = 0.f, bs2 = 0.f, bs3 = 0.f;
    if (layer == 1 && tid < 16) {  // L1 bias per unit (L0 bias folded into xgl)
        int uu = g * 16 + tid;
        bs0 = bih[uu] + bhh[uu];
        bs1 = bih[256 + uu] + bhh[256 + uu];
        bs2 = bih[512 + uu] + bhh[512 + uu];
        bs3 = bih[768 + uu] + bhh[768 + uu];
    }

    // ---- recurrence: 2 barriers/round; cross-WG via tagged payloads ----
    float cst = 0.0f;
    for (int t = 0; t < 16; ++t) {
        if (layer == 0) {
            if (t) hsm[tid] = pollh(&hT0[((b * 16 + t - 1) << 8) + tid], t);
        } else {
            if (t) {
                float2 hv = pollh2(&hT0[((b * 16 + t) << 8) + tid], t + 1,
                                   &hT2[(((b << 1) | ((t - 1) & 1)) << 8) + tid], t);
                hsm[tid] = hv.x; h2sm[tid] = hv.y;
            } else {
                hsm[tid] = pollh(&hT0[((b * 16) << 8) + tid], 1);
            }
        }
        __syncthreads();
        float a = 0.0f;
        if (layer == 0) {
            if (t) {
                const float4* hr = (const float4*)&hsm[krow0];
#pragma unroll
                for (int k = 0; k < 16; ++k) {
                    float4 h = hr[k];
                    a += h.x * wvh[k].x + h.y * wvh[k].y + h.z * wvh[k].z + h.w * wvh[k].w;
                }
            }
        } else {
            const float4* xr = (const float4*)&hsm[krow0];
#pragma unroll
            for (int k = 0; k < 16; ++k) {
                float4 x = xr[k];
                a += x.x * wvi[k].x + x.y * wvi[k].y + x.z * wvi[k].z + x.w * wvi[k].w;
            }
            if (t) {
                const float4* hr = (const float4*)&h2sm[krow0];
#pragma unroll
                for (int k = 0; k < 16; ++k) {
                    float4 h = hr[k];
                    a += h.x * wvh[k].x + h.y * wvh[k].y + h.z * wvh[k].z + h.w * wvh[k].w;
                }
            }
        }
        partA[tid] = a;
        __syncthreads();
        if (tid < 16) {  // gather 4 gates x 4 k-quarters, cell update, signal
            float gi, gf, gg, go;
            if (layer == 0) {
                gi = xgl[t * 64 + tid];       gf = xgl[t * 64 + 16 + tid];
                gg = xgl[t * 64 + 32 + tid];  go = xgl[t * 64 + 48 + tid];
            } else { gi = bs0; gf = bs1; gg = bs2; go = bs3; }
#pragma unroll
            for (int q = 0; q < 4; ++q) {
                gi += partA[q * 64 + tid];
                gf += partA[q * 64 + 16 + tid];
                gg += partA[q * 64 + 32 + tid];
                go += partA[q * 64 + 48 + tid];
            }
            float i_ = sigmoidf_(gi), f_ = sigmoidf_(gf);
            float g_ = tanhf(gg), o_ = sigmoidf_(go);
            cst = f_ * cst + i_ * g_;
            float h = o_ * tanhf(cst);
            int unit = g * 16 + tid;
            if (layer == 0) {
                storeh(&hT0[((b * 16 + t) << 8) + unit], h, t + 1);
            } else {
                storeh(&hT2[(((b << 1) | (t & 1)) << 8) + unit], h, t + 1);
                out[OUT_MF + (b * 16 + t) * 256 + unit] = h;
            }
        }
        // no trailing barrier: hsm/h2sm/partA rewrites fenced by next round's barriers
    }
    if (layer == 0 || g != 0) return;

    // ---- heads (L1 g==0, one WG per batch) ----
    float* lh = sPX;          // 256
    float* x1 = sPX + 256;    // 256
    float* c1 = sPX + 512;    // 128
    float* x2 = sPX + 640;    // 128
    float* dl = sPX + 768;    // 20
    lh[tid] = pollh(&hT2[(((b << 1) | 1) << 8) + tid], 16);
    if (tid < 32) {  // bbox of image b*16+15 for cumsum base
        int4 v = pm4[(b * 16 + 15) * 32 + tid];
        int xmn = v.x, xmx = v.y, ymn = v.z, ymx = v.w;
        for (int off = 16; off > 0; off >>= 1) {
            xmn = min(xmn, __shfl_down(xmn, off, 32));
            xmx = max(xmx, __shfl_down(xmx, off, 32));
            ymn = min(ymn, __shfl_down(ymn, off, 32));
            ymx = max(ymx, __shfl_down(ymx, off, 32));
        }
        if (tid == 0) mk_bbox(xmn, xmx, ymn, ymx, sBB);
    }
    __syncthreads();
    {
        float a = mp_b1[tid];
#pragma unroll 4
        for (int k = 0; k < 256; ++k) a += lh[k] * mp_w1[k * 256 + tid];
        x1[tid] = fmaxf(a, 0.0f);
    }
    if (tid < 128) {
        float a = cf_b1[tid];
#pragma unroll 4
        for (int k = 0; k < 256; ++k) a += lh[k] * cf_w1[k * 128 + tid];
        c1[tid] = fmaxf(a, 0.0f);
    }
    __syncthreads();
    if (tid < 128) {
        float a = mp_b2[tid];
#pragma unroll 4
        for (int k = 0; k < 256; ++k) a += x1[k] * mp_w2[k * 128 + tid];
        x2[tid] = fmaxf(a, 0.0f);
    } else if (tid < 133) {
        int jj = tid - 128;
        float a = cf_b2[jj];
#pragma unroll 4
        for (int k = 0; k < 128; ++k) a += c1[k] * cf_w2[k * 5 + jj];
        out[OUT_CONF + b * 5 + jj] = sigmoidf_(a);
    }
    __syncthreads();
    if (tid < 20) {
        float a = mp_b3[tid];
#pragma unroll 4
        for (int k = 0; k < 128; ++k) a += x2[k] * mp_w3[k * 20 + tid];
        dl[tid] = a;
        out[OUT_DELTAS + b * 20 + tid] = a;
    }
    __syncthreads();
    if (tid < 4) {
        float acc = sBB[tid];
        for (int hh = 0; hh < 5; ++hh) {
            acc += dl[hh * 4 + tid];
            out[OUT_PBB + b * 20 + hh * 4 + tid] = acc;
            if (tid < 2) out[OUT_LOC + b * 10 + hh * 2 + tid] = acc;
            else out[OUT_SCL + b * 10 + hh * 2 + (tid - 2)] = acc;
        }
    }
    __syncthreads();
    if (tid == 0) atomicAdd(done, 1);  // release clock-keeper fillers
}

extern "C" void kernel_launch(void* const* d_in, const int* in_sizes, int n_in,
                              void* d_out, int out_size, void* d_ws, size_t ws_size,
                              hipStream_t stream) {
    (void)in_sizes; (void)n_in; (void)out_size; (void)ws_size;
    const float* pred = (const float*)d_in[1];  // d_in[0] = features (unused)
    const float* pe_w1 = (const float*)d_in[2];
    const float* pe_b1 = (const float*)d_in[3];
    const float* pe_w2 = (const float*)d_in[4];
    const float* pe_b2 = (const float*)d_in[5];
    const float* wih0 = (const float*)d_in[6];
    const float* whh0 = (const float*)d_in[7];
    const float* bih0 = (const float*)d_in[8];
    const float* bhh0 = (const float*)d_in[9];
    const float* wih1 = (const float*)d_in[10];
    const float* whh1 = (const float*)d_in[11];
    const float* bih1 = (const float*)d_in[12];
    const float* bhh1 = (const float*)d_in[13];
    const float* mp_w1 = (const float*)d_in[14];
    const float* mp_b1 = (const float*)d_in[15];
    const float* mp_w2 = (const float*)d_in[16];
    const float* mp_b2 = (const float*)d_in[17];
    const float* mp_w3 = (const float*)d_in[18];
    const float* mp_b3 = (const float*)d_in[19];
    const float* cf_w1 = (const float*)d_in[20];
    const float* cf_b1 = (const float*)d_in[21];
    const float* cf_w2 = (const float*)d_in[22];
    const float* cf_b2 = (const float*)d_in[23];
    float* out = (float*)d_out;
    int* wsi = (int*)d_ws;

    hipLaunchKernelGGL(k_minmax, dim3(64 * 32), dim3(256), 0, stream,
                       (const float4*)pred, wsi);
    hipLaunchKernelGGL(k_fused, dim3(256), dim3(256), 0, stream,
                       pe_w1, pe_b1, pe_w2, pe_b2,
                       wih0, whh0, bih0, bhh0,
                       wih1, whh1, bih1, bhh1,
                       mp_w1, mp_b1, mp_w2, mp_b2, mp_w3, mp_b3,
                       cf_w1, cf_b1, cf_w2, cf_b2,
                       (const int4*)(wsi + PM_OFF),
                       (unsigned long long*)(wsi + HT0_OFF),
                       (unsigned long long*)(wsi + HT2_OFF),
                       wsi + DONE_OFF, out);
}

// Round 7
// 559.013 us; speedup vs baseline: 1.9562x; 1.0633x over previous
//
#include <hip/hip_runtime.h>
#include <math.h>

#define BIGI (1 << 30)

// ---- workspace layout (4-byte words), total 176128 words = 688 KB ----
#define PM_OFF    0         // 2048 x int4 minmax partials
#define HT0_OFF   8192      // 4 x 16 x 256 tagged u64 (h1 history)
#define HT2_OFF   40960     // 4 x 2 x 256 tagged u64 (h2 double buffer)
#define XG1_OFF   45056     // 4 x 16 x 1024 tagged u64 (xg1 per t)
#define ZERO_BEG  8192
#define ZERO_END  176128

// ---- output layout (floats) ----
#define OUT_DELTAS 0       // (4,5,4)
#define OUT_PBB    80      // (4,5,4)
#define OUT_LOC    160     // (4,5,2)
#define OUT_SCL    200     // (4,5,2)
#define OUT_MF     240     // (4,16,256)
#define OUT_CONF   16624   // (4,5)
#define OUT_BBOX   16644   // (4,16,4)

__device__ __forceinline__ float sigmoidf_(float x) { return 1.0f / (1.0f + expf(-x)); }

// ---- self-signaling exchange: one 8B atomic payload = (tag<<32)|float ----
__device__ __forceinline__ void storeh(unsigned long long* p, float h, int tag) {
    unsigned long long v =
        ((unsigned long long)(unsigned)tag << 32) | (unsigned long long)__float_as_uint(h);
    __hip_atomic_store(p, v, __ATOMIC_RELAXED, __HIP_MEMORY_SCOPE_AGENT);
}
__device__ __forceinline__ float pollh(const unsigned long long* p, int tag) {
    unsigned long long v = __hip_atomic_load(p, __ATOMIC_RELAXED, __HIP_MEMORY_SCOPE_AGENT);
    while ((int)(v >> 32) != tag) {
        __builtin_amdgcn_s_sleep(1);
        v = __hip_atomic_load(p, __ATOMIC_RELAXED, __HIP_MEMORY_SCOPE_AGENT);
    }
    return __uint_as_float((unsigned)v);
}

// ---------------- kernel 1: minmax partials + zero tag region ----------------
__global__ __launch_bounds__(256) void k_minmax(const float4* __restrict__ pred,
                                                int* __restrict__ ws) {
    int tid = threadIdx.x;
    {   // zero tagged regions (blocks 0..655 each cover 256 words)
        int i = ZERO_BEG + blockIdx.x * 256 + tid;
        if (i < ZERO_END) ws[i] = 0;
    }
    int img = blockIdx.x >> 5;
    int chunk = blockIdx.x & 31;
    int base = img * 262144 + chunk * 8192 + tid;
    int xmn = BIGI, xmx = -1, ymn = BIGI, ymx = -1;
#pragma unroll 4
    for (int i = 0; i < 32; ++i) {
        int idx4 = base + i * 256;
        float4 v = pred[idx4];
        int x = (idx4 << 2) & 1023;
        int y = (idx4 >> 8) & 1023;
        bool m0 = v.x > 0.5f, m1 = v.y > 0.5f, m2 = v.z > 0.5f, m3 = v.w > 0.5f;
        int cmn = m0 ? x : (m1 ? x + 1 : (m2 ? x + 2 : (m3 ? x + 3 : BIGI)));
        int cmx = m3 ? x + 3 : (m2 ? x + 2 : (m1 ? x + 1 : (m0 ? x : -1)));
        xmn = min(xmn, cmn);
        xmx = max(xmx, cmx);
        if (m0 | m1 | m2 | m3) { ymn = min(ymn, y); ymx = max(ymx, y); }
    }
    for (int off = 32; off > 0; off >>= 1) {
        xmn = min(xmn, __shfl_down(xmn, off));
        xmx = max(xmx, __shfl_down(xmx, off));
        ymn = min(ymn, __shfl_down(ymn, off));
        ymx = max(ymx, __shfl_down(ymx, off));
    }
    __shared__ int red[4][4];
    int wave = tid >> 6;
    if ((tid & 63) == 0) { red[0][wave] = xmn; red[1][wave] = xmx; red[2][wave] = ymn; red[3][wave] = ymx; }
    __syncthreads();
    if (tid == 0) {
        xmn = min(min(red[0][0], red[0][1]), min(red[0][2], red[0][3]));
        xmx = max(max(red[1][0], red[1][1]), max(red[1][2], red[1][3]));
        ymn = min(min(red[2][0], red[2][1]), min(red[2][2], red[2][3]));
        ymx = max(max(red[3][0], red[3][1]), max(red[3][2], red[3][3]));
        ((int4*)(ws + PM_OFF))[blockIdx.x] = make_int4(xmn, xmx, ymn, ymx);
    }
}

__device__ __forceinline__ void mk_bbox(int xmn, int xmx, int ymn, int ymx, float* o) {
    if (xmx >= 0) {
        o[0] = (float)(xmn + xmx) * (0.5f / 1024.0f);
        o[1] = (float)(ymn + ymx) * (0.5f / 1024.0f);
        o[2] = (float)(xmx - xmn) * (1.0f / 1024.0f);
        o[3] = (float)(ymx - ymn) * (1.0f / 1024.0f);
    } else { o[0] = 0.5f; o[1] = 0.5f; o[2] = 0.1f; o[3] = 0.1f; }
}

// ---------------- kernel 2: 3-stage pipelined LSTM + heads ----------------
// 48 WGs x 512 threads. blk>>4 = stage (0:L0rec whh0, 1:L1xg wih1, 2:L1rec whh1);
// b=(blk>>2)&3, g=blk&3. Each WG owns 256 gate-cols: c=tid&255, kh=tid>>8,
// col = (c>>6)*256 + g*64 + (c&63); thread holds 128 rows x 1 col = wreg[32]
// float4 = 128 VGPRs -- ONE matrix per code path (allocator-proven regime, R3/R4).
__global__ __launch_bounds__(512, 2) void k_fused(
    const float* __restrict__ pe_w1, const float* __restrict__ pe_b1,
    const float* __restrict__ pe_w2, const float* __restrict__ pe_b2,
    const float* __restrict__ wih0, const float* __restrict__ whh0,
    const float* __restrict__ bih0, const float* __restrict__ bhh0,
    const float* __restrict__ wih1, const float* __restrict__ whh1,
    const float* __restrict__ bih1, const float* __restrict__ bhh1,
    const float* __restrict__ mp_w1, const float* __restrict__ mp_b1,
    const float* __restrict__ mp_w2, const float* __restrict__ mp_b2,
    const float* __restrict__ mp_w3, const float* __restrict__ mp_b3,
    const float* __restrict__ cf_w1, const float* __restrict__ cf_b1,
    const float* __restrict__ cf_w2, const float* __restrict__ cf_b2,
    const int4* __restrict__ pm4, unsigned long long* __restrict__ hT0,
    unsigned long long* __restrict__ hT2, unsigned long long* __restrict__ xg1,
    float* __restrict__ out) {
    __shared__ __align__(16) float sA[4096];  // L0rec: pos2; L1rec g0: heads scratch
    __shared__ __align__(16) float sB[4096];  // L0rec: p1 then xg0[t][c]
    __shared__ __align__(16) float hsm[256];  // polled h (h1 or h2)
    __shared__ float xsm[256];                // L1rec: polled xg1[t]
    __shared__ float partA[512];
    __shared__ float sBB[64];
    const int tid = threadIdx.x, blk = blockIdx.x;
    const int stage = blk >> 4;
    const int b = (blk >> 2) & 3, g = blk & 3;
    const int c = tid & 255, kh = tid >> 8;
    const int col = ((c >> 6) << 8) + g * 64 + (c & 63);
    const int krow0 = kh * 128;

    float4 wreg[32];
    float cst = 0.0f;

    if (stage == 0) {
        // ======================= L0rec =======================
        {   // bbox for 16 images: thread = (il = tid>>5, ch = tid&31)
            int il = tid >> 5, ch = tid & 31;
            int4 v = pm4[(b * 16 + il) * 32 + ch];
            int xmn = v.x, xmx = v.y, ymn = v.z, ymx = v.w;
            for (int off = 16; off > 0; off >>= 1) {
                xmn = min(xmn, __shfl_down(xmn, off, 32));
                xmx = max(xmx, __shfl_down(xmx, off, 32));
                ymn = min(ymn, __shfl_down(ymn, off, 32));
                ymx = max(ymx, __shfl_down(ymx, off, 32));
            }
            if (ch == 0) {
                float bb[4];
                mk_bbox(xmn, xmx, ymn, ymx, bb);
                sBB[il * 4 + 0] = bb[0]; sBB[il * 4 + 1] = bb[1];
                sBB[il * 4 + 2] = bb[2]; sBB[il * 4 + 3] = bb[3];
                if (g == 0) {
                    out[OUT_BBOX + (b * 16 + il) * 4 + 0] = bb[0];
                    out[OUT_BBOX + (b * 16 + il) * 4 + 1] = bb[1];
                    out[OUT_BBOX + (b * 16 + il) * 4 + 2] = bb[2];
                    out[OUT_BBOX + (b * 16 + il) * 4 + 3] = bb[3];
                }
            }
        }
        __syncthreads();
        if (tid < 256) {  // p1[i][tid], 16 rows
            float w0 = pe_w1[tid], w1 = pe_w1[256 + tid];
            float w2 = pe_w1[512 + tid], w3 = pe_w1[768 + tid], b1v = pe_b1[tid];
#pragma unroll
            for (int i = 0; i < 16; ++i) {
                float v = sBB[i * 4] * w0 + sBB[i * 4 + 1] * w1 +
                          sBB[i * 4 + 2] * w2 + sBB[i * 4 + 3] * w3 + b1v;
                sB[i * 256 + tid] = fmaxf(v, 0.0f);
            }
        }
        __syncthreads();
        {   // pos2: thread (c, kh) -> rows kh*8..kh*8+8
            int i0 = kh * 8;
            float acc[8];
            float b2v = pe_b2[c];
#pragma unroll
            for (int i = 0; i < 8; ++i) acc[i] = b2v;
            for (int k = 0; k < 256; ++k) {
                float wv = pe_w2[k * 256 + c];
#pragma unroll
                for (int i = 0; i < 8; ++i) acc[i] += sB[(i0 + i) * 256 + k] * wv;
            }
#pragma unroll
            for (int i = 0; i < 8; ++i) sA[(i0 + i) * 256 + c] = fmaxf(acc[i], 0.0f);
        }
        __syncthreads();
#pragma unroll
        for (int k4 = 0; k4 < 32; ++k4) {  // wih0 slice (transient)
            int r = krow0 + k4 * 4;
            wreg[k4].x = wih0[(r + 0) * 1024 + col];
            wreg[k4].y = wih0[(r + 1) * 1024 + col];
            wreg[k4].z = wih0[(r + 2) * 1024 + col];
            wreg[k4].w = wih0[(r + 3) * 1024 + col];
        }
        float xacc[16];
#pragma unroll
        for (int t = 0; t < 16; ++t) {  // xg0 partials, all t
            const float4* pr = (const float4*)&sA[t * 256 + krow0];
            float a = 0.0f;
#pragma unroll
            for (int k = 0; k < 32; ++k) {
                float4 x = pr[k];
                a += x.x * wreg[k].x + x.y * wreg[k].y + x.z * wreg[k].z + x.w * wreg[k].w;
            }
            xacc[t] = a;
        }
        if (kh == 1) {
#pragma unroll
            for (int t = 0; t < 16; ++t) sB[t * 256 + c] = xacc[t];
        }
        __syncthreads();
        if (kh == 0) {
            float bsum = bih0[col] + bhh0[col];
#pragma unroll
            for (int t = 0; t < 16; ++t) sB[t * 256 + c] = xacc[t] + sB[t * 256 + c] + bsum;
        }
        __syncthreads();
#pragma unroll
        for (int k4 = 0; k4 < 32; ++k4) {  // whh0 slice (resident for t-loop)
            int r = krow0 + k4 * 4;
            wreg[k4].x = whh0[(r + 0) * 1024 + col];
            wreg[k4].y = whh0[(r + 1) * 1024 + col];
            wreg[k4].z = whh0[(r + 2) * 1024 + col];
            wreg[k4].w = whh0[(r + 3) * 1024 + col];
        }
        for (int t = 0; t < 16; ++t) {
            if (t && tid < 256) hsm[tid] = pollh(&hT0[((b * 16 + t - 1) << 8) + tid], t);
            __syncthreads();
            float a = 0.0f;
            if (t) {
                const float4* hr = (const float4*)&hsm[krow0];
#pragma unroll
                for (int k = 0; k < 32; ++k) {
                    float4 h = hr[k];
                    a += h.x * wreg[k].x + h.y * wreg[k].y + h.z * wreg[k].z + h.w * wreg[k].w;
                }
            }
            partA[kh * 256 + c] = a;
            __syncthreads();
            if (tid < 64) {
                int u = tid, unit = g * 64 + u;
                float gi = sB[t * 256 + u]       + partA[u]       + partA[256 + u];
                float gf = sB[t * 256 + 64 + u]  + partA[64 + u]  + partA[320 + u];
                float gg = sB[t * 256 + 128 + u] + partA[128 + u] + partA[384 + u];
                float go = sB[t * 256 + 192 + u] + partA[192 + u] + partA[448 + u];
                float i_ = sigmoidf_(gi), f_ = sigmoidf_(gf);
                float g_ = tanhf(gg), o_ = sigmoidf_(go);
                cst = f_ * cst + i_ * g_;
                float h = o_ * tanhf(cst);
                storeh(&hT0[((b * 16 + t) << 8) + unit], h, t + 1);
            }
        }
        return;
    }

    if (stage == 1) {
        // ======================= L1xg =======================
#pragma unroll
        for (int k4 = 0; k4 < 32; ++k4) {  // wih1 slice (resident)
            int r = krow0 + k4 * 4;
            wreg[k4].x = wih1[(r + 0) * 1024 + col];
            wreg[k4].y = wih1[(r + 1) * 1024 + col];
            wreg[k4].z = wih1[(r + 2) * 1024 + col];
            wreg[k4].w = wih1[(r + 3) * 1024 + col];
        }
        float bsum = 0.0f;
        if (tid < 256) bsum = bih1[col] + bhh1[col];
        for (int t = 0; t < 16; ++t) {
            if (tid < 256) hsm[tid] = pollh(&hT0[((b * 16 + t) << 8) + tid], t + 1);
            __syncthreads();
            const float4* hr = (const float4*)&hsm[krow0];
            float a = 0.0f;
#pragma unroll
            for (int k = 0; k < 32; ++k) {
                float4 h = hr[k];
                a += h.x * wreg[k].x + h.y * wreg[k].y + h.z * wreg[k].z + h.w * wreg[k].w;
            }
            partA[kh * 256 + c] = a;
            __syncthreads();
            if (tid < 256) {
                float v = partA[tid] + partA[256 + tid] + bsum;
                storeh(&xg1[((b * 16 + t) << 10) + col], v, t + 1);
            }
        }
        return;
    }

    // ======================= L1rec (+ heads on g==0) =======================
#pragma unroll
    for (int k4 = 0; k4 < 32; ++k4) {  // whh1 slice (resident)
        int r = krow0 + k4 * 4;
        wreg[k4].x = whh1[(r + 0) * 1024 + col];
        wreg[k4].y = whh1[(r + 1) * 1024 + col];
        wreg[k4].z = whh1[(r + 2) * 1024 + col];
        wreg[k4].w = whh1[(r + 3) * 1024 + col];
    }
    for (int t = 0; t < 16; ++t) {
        if (tid < 256) {  // poll h2[t-1]
            if (t) hsm[tid] = pollh(&hT2[(((b << 1) | ((t - 1) & 1)) << 8) + tid], t);
        } else {          // poll xg1[t] (its own col slice), concurrently
            int cc = tid - 256;
            int colx = ((cc >> 6) << 8) + g * 64 + (cc & 63);
            xsm[cc] = pollh(&xg1[((b * 16 + t) << 10) + colx], t + 1);
        }
        __syncthreads();
        float a = 0.0f;
        if (t) {
            const float4* hr = (const float4*)&hsm[krow0];
#pragma unroll
            for (int k = 0; k < 32; ++k) {
                float4 h = hr[k];
                a += h.x * wreg[k].x + h.y * wreg[k].y + h.z * wreg[k].z + h.w * wreg[k].w;
            }
        }
        partA[kh * 256 + c] = a;
        __syncthreads();
        if (tid < 64) {
            int u = tid, unit = g * 64 + u;
            float gi = xsm[u]       + partA[u]       + partA[256 + u];
            float gf = xsm[64 + u]  + partA[64 + u]  + partA[320 + u];
            float gg = xsm[128 + u] + partA[128 + u] + partA[384 + u];
            float go = xsm[192 + u] + partA[192 + u] + partA[448 + u];
            float i_ = sigmoidf_(gi), f_ = sigmoidf_(gf);
            float g_ = tanhf(gg), o_ = sigmoidf_(go);
            cst = f_ * cst + i_ * g_;
            float h = o_ * tanhf(cst);
            storeh(&hT2[(((b << 1) | (t & 1)) << 8) + unit], h, t + 1);
            out[OUT_MF + (b * 16 + t) * 256 + unit] = h;
        }
    }
    if (g != 0) return;

    // ---- heads (one WG per batch) ----
    float* lh = sA;          // 256
    float* x1 = sA + 256;    // 256
    float* c1 = sA + 512;    // 128
    float* x2 = sA + 640;    // 128
    float* dl = sA + 768;    // 20
    if (tid < 256) lh[tid] = pollh(&hT2[(((b << 1) | 1) << 8) + tid], 16);
    if (tid < 32) {  // bbox of image b*16+15
        int4 v = pm4[(b * 16 + 15) * 32 + tid];
        int xmn = v.x, xmx = v.y, ymn = v.z, ymx = v.w;
        for (int off = 16; off > 0; off >>= 1) {
            xmn = min(xmn, __shfl_down(xmn, off, 32));
            xmx = max(xmx, __shfl_down(xmx, off, 32));
            ymn = min(ymn, __shfl_down(ymn, off, 32));
            ymx = max(ymx, __shfl_down(ymx, off, 32));
        }
        if (tid == 0) mk_bbox(xmn, xmx, ymn, ymx, sBB);
    }
    __syncthreads();
    if (tid < 256) {
        float a = mp_b1[tid];
#pragma unroll 4
        for (int k = 0; k < 256; ++k) a += lh[k] * mp_w1[k * 256 + tid];
        x1[tid] = fmaxf(a, 0.0f);
    } else if (tid < 384) {
        int jj = tid - 256;
        float a = cf_b1[jj];
#pragma unroll 4
        for (int k = 0; k < 256; ++k) a += lh[k] * cf_w1[k * 128 + jj];
        c1[jj] = fmaxf(a, 0.0f);
    }
    __syncthreads();
    if (tid < 128) {
        float a = mp_b2[tid];
#pragma unroll 4
        for (int k = 0; k < 256; ++k) a += x1[k] * mp_w2[k * 128 + tid];
        x2[tid] = fmaxf(a, 0.0f);
    } else if (tid >= 256 && tid < 261) {
        int jj = tid - 256;
        float a = cf_b2[jj];
#pragma unroll 4
        for (int k = 0; k < 128; ++k) a += c1[k] * cf_w2[k * 5 + jj];
        out[OUT_CONF + b * 5 + jj] = sigmoidf_(a);
    }
    __syncthreads();
    if (tid < 20) {
        float a = mp_b3[tid];
#pragma unroll 4
        for (int k = 0; k < 128; ++k) a += x2[k] * mp_w3[k * 20 + tid];
        dl[tid] = a;
        out[OUT_DELTAS + b * 20 + tid] = a;
    }
    __syncthreads();
    if (tid < 4) {
        float acc = sBB[tid];
        for (int hh = 0; hh < 5; ++hh) {
            acc += dl[hh * 4 + tid];
            out[OUT_PBB + b * 20 + hh * 4 + tid] = acc;
            if (tid < 2) out[OUT_LOC + b * 10 + hh * 2 + tid] = acc;
            else out[OUT_SCL + b * 10 + hh * 2 + (tid - 2)] = acc;
        }
    }
}

extern "C" void kernel_launch(void* const* d_in, const int* in_sizes, int n_in,
                              void* d_out, int out_size, void* d_ws, size_t ws_size,
                              hipStream_t stream) {
    (void)in_sizes; (void)n_in; (void)out_size; (void)ws_size;
    const float* pred = (const float*)d_in[1];  // d_in[0] = features (unused)
    const float* pe_w1 = (const float*)d_in[2];
    const float* pe_b1 = (const float*)d_in[3];
    const float* pe_w2 = (const float*)d_in[4];
    const float* pe_b2 = (const float*)d_in[5];
    const float* wih0 = (const float*)d_in[6];
    const float* whh0 = (const float*)d_in[7];
    const float* bih0 = (const float*)d_in[8];
    const float* bhh0 = (const float*)d_in[9];
    const float* wih1 = (const float*)d_in[10];
    const float* whh1 = (const float*)d_in[11];
    const float* bih1 = (const float*)d_in[12];
    const float* bhh1 = (const float*)d_in[13];
    const float* mp_w1 = (const float*)d_in[14];
    const float* mp_b1 = (const float*)d_in[15];
    const float* mp_w2 = (const float*)d_in[16];
    const float* mp_b2 = (const float*)d_in[17];
    const float* mp_w3 = (const float*)d_in[18];
    const float* mp_b3 = (const float*)d_in[19];
    const float* cf_w1 = (const float*)d_in[20];
    const float* cf_b1 = (const float*)d_in[21];
    const float* cf_w2 = (const float*)d_in[22];
    const float* cf_b2 = (const float*)d_in[23];
    float* out = (float*)d_out;
    int* wsi = (int*)d_ws;

    hipLaunchKernelGGL(k_minmax, dim3(64 * 32), dim3(256), 0, stream,
                       (const float4*)pred, wsi);
    hipLaunchKernelGGL(k_fused, dim3(48), dim3(512), 0, stream,
                       pe_w1, pe_b1, pe_w2, pe_b2,
                       wih0, whh0, bih0, bhh0,
                       wih1, whh1, bih1, bhh1,
                       mp_w1, mp_b1, mp_w2, mp_b2, mp_w3, mp_b3,
                       cf_w1, cf_b1, cf_w2, cf_b2,
                       (const int4*)(wsi + PM_OFF),
                       (unsigned long long*)(wsi + HT0_OFF),
                       (unsigned long long*)(wsi + HT2_OFF),
                       (unsigned long long*)(wsi + XG1_OFF),
                       out);
}